// Round 4
// baseline (3146.407 us; speedup 1.0000x reference)
//
#include <hip/hip_runtime.h>

#define KDIM 64
#define BROWS 256          // rows per bucket (bkt = row >> 8)
#define NBPAD 512          // padded bucket-array size (NB = 274 here)
#define CHUNK 4096         // records per bin_scatter / bucket_count block

__device__ __forceinline__ float bf16u_to_f(unsigned short u) {
    return __uint_as_float(((unsigned)u) << 16);
}
__device__ __forceinline__ float bf16lo(unsigned u) {
    return __uint_as_float(u << 16);
}
__device__ __forceinline__ float bf16hi(unsigned u) {
    return __uint_as_float(u & 0xFFFF0000u);
}
__device__ __forceinline__ unsigned short f_to_bf16u(float f) {
    unsigned b = __float_as_uint(f);
    b += 0x7FFF + ((b >> 16) & 1);          // round-to-nearest-even
    return (unsigned short)(b >> 16);
}

// Unified row decode over the 4 concatenated edge lists.
// Row space: [0,S) students (ui1,ui0), [S,S+E) exercises (iu1,iu0).
__device__ __forceinline__ int dec_row(int e,
    const int* __restrict__ i1, const int* __restrict__ i0,
    const int* __restrict__ j1, const int* __restrict__ j0,
    int n1, int n0, int m1, int S_)
{
    if (e < n1) return i1[e];
    e -= n1;
    if (e < n0) return i0[e];
    e -= n0;
    if (e < m1) return S_ + j1[e];
    e -= m1;
    return S_ + j0[e];
}

__device__ __forceinline__ void dec_full(int e,
    const int* __restrict__ i1, const float* __restrict__ v1,
    const int* __restrict__ i0, const float* __restrict__ v0,
    const int* __restrict__ j1, const float* __restrict__ w1,
    const int* __restrict__ j0, const float* __restrict__ w0,
    int n1, int n0, int m1, int S_,
    unsigned& row, unsigned& pk)
{
    int col; float v;
    if (e < n1) { row = (unsigned)i1[e]; col = i1[n1 + e]; v = v1[e]; }
    else {
        e -= n1;
        if (e < n0) { row = (unsigned)i0[e]; col = i0[n0 + e]; v = v0[e]; }
        else {
            e -= n0;
            if (e < m1) { row = (unsigned)(S_ + j1[e]); col = j1[m1 + e]; v = w1[e]; }
            else { e -= m1; row = (unsigned)(S_ + j0[e]); col = j0[((int)0) + e + e - e + e]; v = w0[e];
                   // (col = j0[m0 + e]; written plainly below)
            }
        }
    }
    pk = ((unsigned)col << 16) | (unsigned)f_to_bf16u(v);
}

// NOTE: dec_full above had an index typo risk for the last list; use this clean version.
__device__ __forceinline__ void dec_full2(int e,
    const int* __restrict__ i1, const float* __restrict__ v1,
    const int* __restrict__ i0, const float* __restrict__ v0,
    const int* __restrict__ j1, const float* __restrict__ w1,
    const int* __restrict__ j0, const float* __restrict__ w0,
    int n1, int n0, int m1, int m0, int S_,
    unsigned& row, unsigned& pk)
{
    int col; float v;
    if (e < n1) { row = (unsigned)i1[e]; col = i1[n1 + e]; v = v1[e]; }
    else if (e < n1 + n0) { int le = e - n1; row = (unsigned)i0[le]; col = i0[n0 + le]; v = v0[le]; }
    else if (e < n1 + n0 + m1) { int le = e - n1 - n0; row = (unsigned)(S_ + j1[le]); col = j1[m1 + le]; v = w1[le]; }
    else { int le = e - n1 - n0 - m1; row = (unsigned)(S_ + j0[le]); col = j0[m0 + le]; v = w0[le]; }
    pk = ((unsigned)col << 16) | (unsigned)f_to_bf16u(v);
}

// -------- Phase 1: tab0[row] = sigmoid(emb_row @ know_W^T)  (unified bf16 table)
__global__ __launch_bounds__(256) void embed_sig(
    const float* __restrict__ stuW, const float* __restrict__ exerW,
    const float* __restrict__ knowW,
    unsigned short* __restrict__ tab0, int S, int n_rows)
{
    __shared__ float kwT[64][65];
    for (int i = threadIdx.x; i < 64 * 64; i += 256) {
        int k = i >> 6, d = i & 63;
        kwT[d][k] = knowW[i];
    }
    __syncthreads();

    const int lane = threadIdx.x & 63;
    const int row = blockIdx.x * 4 + (threadIdx.x >> 6);
    if (row >= n_rows) return;
    const float* a = (row < S) ? (stuW + (size_t)row * KDIM)
                               : (exerW + (size_t)(row - S) * KDIM);
    const float4* a4 = (const float4*)a;
    float acc = 0.f;
    #pragma unroll
    for (int d4 = 0; d4 < 16; ++d4) {
        float4 av = a4[d4];
        acc += av.x * kwT[d4 * 4 + 0][lane];
        acc += av.y * kwT[d4 * 4 + 1][lane];
        acc += av.z * kwT[d4 * 4 + 2][lane];
        acc += av.w * kwT[d4 * 4 + 3][lane];
    }
    float s = 1.f / (1.f + __expf(-acc));
    tab0[(size_t)row * KDIM + lane] = f_to_bf16u(s);
}

// -------- bucket histogram (LDS-first, then few global adds)
__global__ __launch_bounds__(256) void bucket_count(
    const int* __restrict__ i1, const int* __restrict__ i0,
    const int* __restrict__ j1, const int* __restrict__ j0,
    int n1, int n0, int m1, int S_,
    int* __restrict__ bktCnt, int ntot, int NB)
{
    __shared__ int h[NBPAD];
    for (int i = threadIdx.x; i < NBPAD; i += 256) h[i] = 0;
    __syncthreads();
    const int e0 = blockIdx.x * CHUNK;
    #pragma unroll
    for (int it = 0; it < 16; ++it) {
        int e = e0 + it * 256 + threadIdx.x;
        if (e < ntot) atomicAdd(&h[dec_row(e, i1, i0, j1, j0, n1, n0, m1, S_) >> 8], 1);
    }
    __syncthreads();
    for (int b = threadIdx.x; b < NB; b += 256)
        if (h[b]) atomicAdd(&bktCnt[b], h[b]);
}

// -------- exclusive scan of NB bucket counts -> bktBase (and cursor copy gcurA)
__global__ __launch_bounds__(256) void scan_tiny(
    const int* __restrict__ bktCnt, int* __restrict__ bktBase,
    int* __restrict__ gcurA, int NB)
{
    __shared__ int s[NBPAD + 1];
    for (int i = threadIdx.x; i < NB; i += 256) s[i] = bktCnt[i];
    __syncthreads();
    if (threadIdx.x == 0) {
        int acc = 0;
        for (int b = 0; b < NB; ++b) { int c = s[b]; s[b] = acc; acc += c; }
        s[NB] = acc;
    }
    __syncthreads();
    for (int i = threadIdx.x; i <= NB; i += 256) bktBase[i] = s[i];
    for (int i = threadIdx.x; i < NB; i += 256) gcurA[i] = s[i];
}

// -------- binned scatter: LDS reorder by bucket, drain contiguous runs.
__global__ __launch_bounds__(256) void bin_scatter(
    const int* __restrict__ i1, const float* __restrict__ v1,
    const int* __restrict__ i0, const float* __restrict__ v0,
    const int* __restrict__ j1, const float* __restrict__ w1,
    const int* __restrict__ j0, const float* __restrict__ w0,
    int n1, int n0, int m1, int m0, int S_,
    int* __restrict__ gcurA,
    unsigned* __restrict__ recPacked, unsigned short* __restrict__ recRow,
    int ntot, int NB)
{
    __shared__ int h[NBPAD], sstart[NBPAD], lbase[NBPAD], gdst[NBPAD];
    __shared__ unsigned stageP[CHUNK];
    __shared__ unsigned short stageR[CHUNK];
    __shared__ unsigned short stageB[CHUNK];
    const int tid = threadIdx.x;
    const int e0 = blockIdx.x * CHUNK;

    for (int i = tid; i < NBPAD; i += 256) h[i] = 0;
    __syncthreads();

    unsigned rrow[16], rpk[16];
    #pragma unroll
    for (int it = 0; it < 16; ++it) {
        int e = e0 + it * 256 + tid;
        if (e < ntot) {
            dec_full2(e, i1, v1, i0, v0, j1, w1, j0, w0, n1, n0, m1, m0, S_,
                      rrow[it], rpk[it]);
            atomicAdd(&h[rrow[it] >> 8], 1);
        } else {
            rrow[it] = 0xFFFFFFFFu;
        }
    }
    __syncthreads();

    {   // exclusive prefix over NB buckets; thread t owns buckets t and t+256
        int acc0 = 0, acc1 = 0;
        for (int b = 0; b < NB; ++b) {
            int hv = h[b];
            if (b < tid)       acc0 += hv;
            if (b < tid + 256) acc1 += hv;
        }
        sstart[tid] = acc0; lbase[tid] = acc0;
        int c0 = h[tid];
        if (c0 > 0) gdst[tid] = atomicAdd(&gcurA[tid], c0);
        if (tid + 256 < NB) {
            sstart[tid + 256] = acc1; lbase[tid + 256] = acc1;
            int c1 = h[tid + 256];
            if (c1 > 0) gdst[tid + 256] = atomicAdd(&gcurA[tid + 256], c1);
        }
    }
    __syncthreads();

    #pragma unroll
    for (int it = 0; it < 16; ++it) {
        if (rrow[it] != 0xFFFFFFFFu) {
            int bkt = rrow[it] >> 8;
            int slot = atomicAdd(&lbase[bkt], 1);
            stageP[slot] = rpk[it];
            stageR[slot] = (unsigned short)(rrow[it] & 255u);
            stageB[slot] = (unsigned short)bkt;
        }
    }
    __syncthreads();

    int cnt = ntot - e0; if (cnt > CHUNK) cnt = CHUNK;
    for (int i = tid; i < cnt; i += 256) {
        int bkt = stageB[i];
        int dst = gdst[bkt] + (i - sstart[bkt]);
        recPacked[dst] = stageP[i];
        recRow[dst]   = stageR[i];
    }
}

// -------- bucket pull: one block per 256-row bucket; LDS f32 accumulator.
__global__ __launch_bounds__(256) void bucket_pull(
    const unsigned short* __restrict__ tab0,
    const unsigned* __restrict__ recPacked, const unsigned short* __restrict__ recRow,
    const int* __restrict__ bktBase,
    unsigned short* __restrict__ tabF, int S_, int n_rows)
{
    __shared__ float xacc[BROWS][65];     // pad 65: spreads row-stride over banks
    const int tid = threadIdx.x;
    const int b = blockIdx.x;
    const int r0 = b << 8;
    int nr = n_rows - r0; if (nr > BROWS) nr = BROWS;

    // init with self term x0 = tab0[row]
    for (int i = tid; i < nr * 64; i += 256) {
        int r = i >> 6, k = i & 63;
        xacc[r][k] = bf16u_to_f(tab0[(size_t)(r0 + r) * KDIM + k]);
    }
    __syncthreads();

    const int start = bktBase[b], end = bktBase[b + 1];
    const int lane = tid & 63;
    const int wid  = tid >> 6;
    const int g = lane >> 4;       // which of 4 records in this wave-iteration
    const int s = lane & 15;       // k-range 4s..4s+3

    for (int q = start + wid * 4; q < end; q += 16) {
        int idx = q + g;
        if (idx < end) {
            unsigned pk = recPacked[idx];          // 16-lane broadcast load
            int rowL = (int)recRow[idx];
            float v = __uint_as_float((pk & 0xFFFFu) << 16);
            unsigned col = pk >> 16;
            // student row gathers exercise table (offset S), exercise row gathers student table
            size_t xrow = (r0 + rowL < S_) ? (size_t)((unsigned)S_ + col) : (size_t)col;
            ushort4 xv = *((const ushort4*)(tab0 + (xrow << 6)) + s);
            atomicAdd(&xacc[rowL][4 * s + 0], v * bf16u_to_f(xv.x));
            atomicAdd(&xacc[rowL][4 * s + 1], v * bf16u_to_f(xv.y));
            atomicAdd(&xacc[rowL][4 * s + 2], v * bf16u_to_f(xv.z));
            atomicAdd(&xacc[rowL][4 * s + 3], v * bf16u_to_f(xv.w));
        }
    }
    __syncthreads();

    for (int i = tid; i < nr * 64; i += 256) {
        int r = i >> 6, k = i & 63;
        tabF[(size_t)(r0 + r) * KDIM + k] = f_to_bf16u(xacc[r][k]);
    }
}

// -------- fused gather + NCD MLP. One block = 64 batch rows. bf16 h-tiles.
__global__ __launch_bounds__(256, 1) void tail_mlp(
    const unsigned short* __restrict__ tabF,
    const float* __restrict__ discW,
    const float* __restrict__ W1, const float* __restrict__ b1,
    const float* __restrict__ W2, const float* __restrict__ b2,
    const float* __restrict__ W3, const float* __restrict__ b3,
    const float* __restrict__ kn, const int* __restrict__ stu_id,
    const int* __restrict__ exer_id, float* __restrict__ out, int S_, int B)
{
    __shared__ float xs[64][64];              // 16 KB
    __shared__ unsigned short h1s[64][256];   // 32 KB (bf16)
    __shared__ unsigned short h2s[64][132];   // 16.5 KB (bf16)
    const int tid = threadIdx.x;
    const int b0 = blockIdx.x * 64;

    for (int i = 0; i < 16; ++i) {
        int e = i * 256 + tid;
        int r = e >> 6, k = e & 63;
        int b = b0 + r;
        float x = 0.f;
        if (b < B) {
            int sid = stu_id[b], eid = exer_id[b];
            float disc = 1.f / (1.f + __expf(-discW[eid]));
            float st = bf16u_to_f(tabF[(size_t)sid * KDIM + k]);
            float df = bf16u_to_f(tabF[(size_t)(S_ + eid) * KDIM + k]);
            x = disc * (st - df) * (1.f / 3.f) * kn[(size_t)b * 64 + k];
        }
        xs[r][k] = x;
    }
    __syncthreads();

    {   // h1 = sigmoid(x @ relu(W1) + b1); thread t owns column t
        float w1c[64];
        #pragma unroll
        for (int k = 0; k < 64; ++k) w1c[k] = fmaxf(W1[k * 256 + tid], 0.f);
        const float bb = b1[tid];
        for (int r = 0; r < 64; ++r) {
            const float4* xr = (const float4*)xs[r];
            float acc = bb;
            #pragma unroll
            for (int k4 = 0; k4 < 16; ++k4) {
                float4 xv = xr[k4];
                acc += xv.x * w1c[k4 * 4 + 0] + xv.y * w1c[k4 * 4 + 1]
                     + xv.z * w1c[k4 * 4 + 2] + xv.w * w1c[k4 * 4 + 3];
            }
            h1s[r][tid] = f_to_bf16u(1.f / (1.f + __expf(-acc)));
        }
    }
    __syncthreads();

    {   // h2 = sigmoid(h1 @ relu(W2) + b2)
        const int j = tid & 127;
        const int rg = tid >> 7;
        float acc3[32];
        #pragma unroll
        for (int r = 0; r < 32; ++r) acc3[r] = b2[j];
        for (int kc = 0; kc < 4; ++kc) {
            float w2c[64];
            #pragma unroll
            for (int i = 0; i < 64; ++i) w2c[i] = fmaxf(W2[(kc * 64 + i) * 128 + j], 0.f);
            #pragma unroll 4
            for (int r = 0; r < 32; ++r) {
                const uint4* hr = (const uint4*)&h1s[rg * 32 + r][kc * 64];
                float a = 0.f;
                #pragma unroll
                for (int i4 = 0; i4 < 8; ++i4) {
                    uint4 hv = hr[i4];
                    a = fmaf(bf16lo(hv.x), w2c[i4 * 8 + 0], a);
                    a = fmaf(bf16hi(hv.x), w2c[i4 * 8 + 1], a);
                    a = fmaf(bf16lo(hv.y), w2c[i4 * 8 + 2], a);
                    a = fmaf(bf16hi(hv.y), w2c[i4 * 8 + 3], a);
                    a = fmaf(bf16lo(hv.z), w2c[i4 * 8 + 4], a);
                    a = fmaf(bf16hi(hv.z), w2c[i4 * 8 + 5], a);
                    a = fmaf(bf16lo(hv.w), w2c[i4 * 8 + 6], a);
                    a = fmaf(bf16hi(hv.w), w2c[i4 * 8 + 7], a);
                }
                acc3[r] += a;
            }
        }
        #pragma unroll
        for (int r = 0; r < 32; ++r)
            h2s[rg * 32 + r][j] = f_to_bf16u(1.f / (1.f + __expf(-acc3[r])));
    }
    __syncthreads();

    if (tid < 64) {
        int b = b0 + tid;
        if (b < B) {
            float acc = b3[0];
            const unsigned* h2r = (const unsigned*)&h2s[tid][0];
            for (int jj = 0; jj < 64; ++jj) {
                unsigned hv = h2r[jj];
                acc += bf16lo(hv) * fmaxf(W3[jj * 2 + 0], 0.f)
                     + bf16hi(hv) * fmaxf(W3[jj * 2 + 1], 0.f);
            }
            out[b] = 1.f / (1.f + __expf(-acc));
        }
    }
}

extern "C" void kernel_launch(void* const* d_in, const int* in_sizes, int n_in,
                              void* d_out, int out_size, void* d_ws, size_t ws_size,
                              hipStream_t stream) {
    const float* stuW  = (const float*)d_in[0];
    const float* exerW = (const float*)d_in[1];
    const float* knowW = (const float*)d_in[2];
    const float* discW = (const float*)d_in[3];
    const float* W1 = (const float*)d_in[4];
    const float* b1 = (const float*)d_in[5];
    const float* W2 = (const float*)d_in[6];
    const float* b2 = (const float*)d_in[7];
    const float* W3 = (const float*)d_in[8];
    const float* b3 = (const float*)d_in[9];
    const int*   ui1_idx = (const int*)d_in[10];
    const float* ui1_val = (const float*)d_in[11];
    const int*   ui0_idx = (const int*)d_in[12];
    const float* ui0_val = (const float*)d_in[13];
    const int*   iu1_idx = (const int*)d_in[14];
    const float* iu1_val = (const float*)d_in[15];
    const int*   iu0_idx = (const int*)d_in[16];
    const float* iu0_val = (const float*)d_in[17];
    const float* kn      = (const float*)d_in[18];
    const int*   stu_id  = (const int*)d_in[19];
    const int*   exer_id = (const int*)d_in[20];
    float* out = (float*)d_out;

    const int S = in_sizes[0] / KDIM;
    const int E = in_sizes[1] / KDIM;
    const int B = in_sizes[19];
    const int n1 = in_sizes[11], n0 = in_sizes[13];
    const int m1 = in_sizes[15], m0 = in_sizes[17];
    const int ntot = n1 + n0 + m1 + m0;
    const int n_rows = S + E;
    const int NB = (n_rows + BROWS - 1) / BROWS;       // 274
    const int nchunks = (ntot + CHUNK - 1) / CHUNK;

    char* p = (char*)d_ws;
    unsigned short* tab0 = (unsigned short*)p; p += (size_t)n_rows * KDIM * 2;
    unsigned short* tabF = (unsigned short*)p; p += (size_t)n_rows * KDIM * 2;
    unsigned* recPacked  = (unsigned*)p;       p += (size_t)ntot * 4;
    unsigned short* recRow = (unsigned short*)p; p += (size_t)ntot * 2;
    int* bktCnt  = (int*)p;                    p += (size_t)(NB + 2) * 4;
    int* bktBase = (int*)p;                    p += (size_t)(NB + 2) * 4;
    int* gcurA   = (int*)p;                    p += (size_t)(NB + 2) * 4;

    hipMemsetAsync(bktCnt, 0, (size_t)NB * 4, stream);

    embed_sig<<<(n_rows + 3) / 4, 256, 0, stream>>>(stuW, exerW, knowW, tab0, S, n_rows);

    bucket_count<<<nchunks, 256, 0, stream>>>(ui1_idx, ui0_idx, iu1_idx, iu0_idx,
                                              n1, n0, m1, S, bktCnt, ntot, NB);

    scan_tiny<<<1, 256, 0, stream>>>(bktCnt, bktBase, gcurA, NB);

    bin_scatter<<<nchunks, 256, 0, stream>>>(
        ui1_idx, ui1_val, ui0_idx, ui0_val, iu1_idx, iu1_val, iu0_idx, iu0_val,
        n1, n0, m1, m0, S, gcurA, recPacked, recRow, ntot, NB);

    bucket_pull<<<NB, 256, 0, stream>>>(tab0, recPacked, recRow, bktBase,
                                        tabF, S, n_rows);

    tail_mlp<<<(B + 63) / 64, 256, 0, stream>>>(tabF, discW,
                                                W1, b1, W2, b2, W3, b3,
                                                kn, stu_id, exer_id, out, S, B);
}

// Round 5
// 529.118 us; speedup vs baseline: 5.9465x; 5.9465x over previous
//
#include <hip/hip_runtime.h>

#define KDIM 64
#define NBPAD 512          // padded bucket-array size (NB = 274 here)
#define CHUNK 4096         // records per bin_scatter block

__device__ __forceinline__ float bf16u_to_f(unsigned short u) {
    return __uint_as_float(((unsigned)u) << 16);
}
__device__ __forceinline__ float bf16lo(unsigned u) {
    return __uint_as_float(u << 16);
}
__device__ __forceinline__ float bf16hi(unsigned u) {
    return __uint_as_float(u & 0xFFFF0000u);
}
__device__ __forceinline__ unsigned short f_to_bf16u(float f) {
    unsigned b = __float_as_uint(f);
    b += 0x7FFF + ((b >> 16) & 1);          // round-to-nearest-even
    return (unsigned short)(b >> 16);
}

// Unified row space over the 4 concatenated edge lists:
// [0,S) students (ui1,ui0), [S,S+E) exercises (iu1,iu0).
__device__ __forceinline__ int dec_row(int e,
    const int* __restrict__ i1, const int* __restrict__ i0,
    const int* __restrict__ j1, const int* __restrict__ j0,
    int n1, int n0, int m1, int S_)
{
    if (e < n1) return i1[e];
    e -= n1;
    if (e < n0) return i0[e];
    e -= n0;
    if (e < m1) return S_ + j1[e];
    e -= m1;
    return S_ + j0[e];
}

__device__ __forceinline__ void dec_full(int e,
    const int* __restrict__ i1, const float* __restrict__ v1,
    const int* __restrict__ i0, const float* __restrict__ v0,
    const int* __restrict__ j1, const float* __restrict__ w1,
    const int* __restrict__ j0, const float* __restrict__ w0,
    int n1, int n0, int m1, int m0, int S_,
    unsigned& row, unsigned& pk)
{
    int col; float v;
    if (e < n1) { row = (unsigned)i1[e]; col = i1[n1 + e]; v = v1[e]; }
    else if (e < n1 + n0) { int le = e - n1; row = (unsigned)i0[le]; col = i0[n0 + le]; v = v0[le]; }
    else if (e < n1 + n0 + m1) { int le = e - n1 - n0; row = (unsigned)(S_ + j1[le]); col = j1[m1 + le]; v = w1[le]; }
    else { int le = e - n1 - n0 - m1; row = (unsigned)(S_ + j0[le]); col = j0[m0 + le]; v = w0[le]; }
    pk = ((unsigned)col << 16) | (unsigned)f_to_bf16u(v);
}

// -------- Phase 1: tab0[row] = sigmoid(emb_row @ know_W^T)  (unified bf16 table)
__global__ __launch_bounds__(256) void embed_sig(
    const float* __restrict__ stuW, const float* __restrict__ exerW,
    const float* __restrict__ knowW,
    unsigned short* __restrict__ tab0, int S, int n_rows)
{
    __shared__ float kwT[64][65];
    for (int i = threadIdx.x; i < 64 * 64; i += 256) {
        int k = i >> 6, d = i & 63;
        kwT[d][k] = knowW[i];
    }
    __syncthreads();

    const int lane = threadIdx.x & 63;
    const int row = blockIdx.x * 4 + (threadIdx.x >> 6);
    if (row >= n_rows) return;
    const float* a = (row < S) ? (stuW + (size_t)row * KDIM)
                               : (exerW + (size_t)(row - S) * KDIM);
    const float4* a4 = (const float4*)a;
    float acc = 0.f;
    #pragma unroll
    for (int d4 = 0; d4 < 16; ++d4) {
        float4 av = a4[d4];
        acc += av.x * kwT[d4 * 4 + 0][lane];
        acc += av.y * kwT[d4 * 4 + 1][lane];
        acc += av.z * kwT[d4 * 4 + 2][lane];
        acc += av.w * kwT[d4 * 4 + 3][lane];
    }
    float s = 1.f / (1.f + __expf(-acc));
    tab0[(size_t)row * KDIM + lane] = f_to_bf16u(s);
}

// -------- per-row histogram (counts land in rowCur; scan pipeline converts to cursors)
__global__ __launch_bounds__(256) void row_count(
    const int* __restrict__ i1, const int* __restrict__ i0,
    const int* __restrict__ j1, const int* __restrict__ j0,
    int n1, int n0, int m1, int S_, int* __restrict__ rowCur, int ntot)
{
    int e = blockIdx.x * 256 + threadIdx.x;
    if (e < ntot) atomicAdd(&rowCur[dec_row(e, i1, i0, j1, j0, n1, n0, m1, S_)], 1);
}

// -------- scan step a: per-1024-chunk sums
__global__ __launch_bounds__(256) void scan_partial(
    const int* __restrict__ cnt, int* __restrict__ bsum, int n)
{
    __shared__ int red[256];
    int b = blockIdx.x;
    int s = 0;
    for (int i = threadIdx.x; i < 1024; i += 256) {
        int g = b * 1024 + i;
        if (g < n) s += cnt[g];
    }
    red[threadIdx.x] = s;
    __syncthreads();
    for (int o = 128; o > 0; o >>= 1) {
        if (threadIdx.x < o) red[threadIdx.x] += red[threadIdx.x + o];
        __syncthreads();
    }
    if (threadIdx.x == 0) bsum[b] = red[0];
}

// -------- scan step b: scan the chunk sums (nb <= 256)
__global__ __launch_bounds__(256) void scan_bsum(
    int* __restrict__ bsum, int nb, int* __restrict__ ptr, int n)
{
    __shared__ int s[256];
    int t = threadIdx.x;
    int v = (t < nb) ? bsum[t] : 0;
    s[t] = v;
    __syncthreads();
    for (int o = 1; o < 256; o <<= 1) {
        int add = (t >= o) ? s[t - o] : 0;
        __syncthreads();
        s[t] += add;
        __syncthreads();
    }
    if (t < nb) bsum[t] = s[t] - v;       // exclusive
    if (t == nb - 1) ptr[n] = s[t];       // grand total
}

// -------- scan step c: exclusive scan -> ptr; rowCur (in-place) = cursor copy;
//          gcurA[bucket] = ptr at each 256-row boundary (bucket scatter cursors).
__global__ __launch_bounds__(256) void scan_final(
    const int* __restrict__ bsum,
    int* __restrict__ ptr, int* __restrict__ rowCur, int* __restrict__ gcurA, int n)
{
    __shared__ int ts[256];
    int b = blockIdx.x, t = threadIdx.x;
    int g0 = b * 1024 + t * 4;
    int v[4]; int s = 0;
    #pragma unroll
    for (int i = 0; i < 4; ++i) {
        int g = g0 + i;
        v[i] = (g < n) ? rowCur[g] : 0;   // counts (read before in-place overwrite)
        s += v[i];
    }
    ts[t] = s;
    __syncthreads();
    int mine = s;
    for (int o = 1; o < 256; o <<= 1) {
        int add = (t >= o) ? ts[t - o] : 0;
        __syncthreads();
        ts[t] += add;
        __syncthreads();
    }
    int off = bsum[b] + ts[t] - mine;
    #pragma unroll
    for (int i = 0; i < 4; ++i) {
        int g = g0 + i;
        if (g < n) {
            ptr[g] = off;
            rowCur[g] = off;                      // per-row cursor for row_sort
            if ((g & 255) == 0) gcurA[g >> 8] = off;  // per-bucket cursor
        }
        off += v[i];
    }
}

// -------- binned scatter: LDS reorder by 256-row bucket, drain coalesced runs.
__global__ __launch_bounds__(256) void bin_scatter(
    const int* __restrict__ i1, const float* __restrict__ v1,
    const int* __restrict__ i0, const float* __restrict__ v0,
    const int* __restrict__ j1, const float* __restrict__ w1,
    const int* __restrict__ j0, const float* __restrict__ w0,
    int n1, int n0, int m1, int m0, int S_,
    int* __restrict__ gcurA,
    unsigned* __restrict__ recPacked, unsigned char* __restrict__ recRow,
    int ntot, int NB)
{
    __shared__ int h[NBPAD], sstart[NBPAD], lbase[NBPAD], gdst[NBPAD];
    __shared__ unsigned stageP[CHUNK];
    __shared__ unsigned char stageR[CHUNK];
    __shared__ unsigned short stageB[CHUNK];
    const int tid = threadIdx.x;
    const int e0 = blockIdx.x * CHUNK;

    for (int i = tid; i < NBPAD; i += 256) h[i] = 0;
    __syncthreads();

    unsigned rrow[16], rpk[16];
    #pragma unroll
    for (int it = 0; it < 16; ++it) {
        int e = e0 + it * 256 + tid;
        if (e < ntot) {
            dec_full(e, i1, v1, i0, v0, j1, w1, j0, w0, n1, n0, m1, m0, S_,
                     rrow[it], rpk[it]);
            atomicAdd(&h[rrow[it] >> 8], 1);
        } else {
            rrow[it] = 0xFFFFFFFFu;
        }
    }
    __syncthreads();

    {   // exclusive prefix over NB buckets; thread t owns buckets t and t+256
        int acc0 = 0, acc1 = 0;
        for (int b = 0; b < NB; ++b) {
            int hv = h[b];
            if (b < tid)       acc0 += hv;
            if (b < tid + 256) acc1 += hv;
        }
        sstart[tid] = acc0; lbase[tid] = acc0;
        int c0 = h[tid];
        if (c0 > 0) gdst[tid] = atomicAdd(&gcurA[tid], c0);
        if (tid + 256 < NB) {
            sstart[tid + 256] = acc1; lbase[tid + 256] = acc1;
            int c1 = h[tid + 256];
            if (c1 > 0) gdst[tid + 256] = atomicAdd(&gcurA[tid + 256], c1);
        }
    }
    __syncthreads();

    #pragma unroll
    for (int it = 0; it < 16; ++it) {
        if (rrow[it] != 0xFFFFFFFFu) {
            int bkt = rrow[it] >> 8;
            int slot = atomicAdd(&lbase[bkt], 1);
            stageP[slot] = rpk[it];
            stageR[slot] = (unsigned char)(rrow[it] & 255u);
            stageB[slot] = (unsigned short)bkt;
        }
    }
    __syncthreads();

    int cnt = ntot - e0; if (cnt > CHUNK) cnt = CHUNK;
    for (int i = tid; i < cnt; i += 256) {
        int bkt = stageB[i];
        int dst = gdst[bkt] + (i - sstart[bkt]);
        recPacked[dst] = stageP[i];
        recRow[dst]   = stageR[i];
    }
}

// -------- per-bucket counting re-scatter into exact per-row CSR position.
// Writes are random only inside the bucket's ~60 KB window -> L2 line reuse.
__global__ __launch_bounds__(256) void row_sort(
    const unsigned* __restrict__ recPacked, const unsigned char* __restrict__ recRow,
    const int* __restrict__ ptr, int* __restrict__ rowCur,
    unsigned* __restrict__ edges, int n_rows)
{
    const int b = blockIdx.x;
    const int r0 = b << 8;
    int rend = r0 + 256; if (rend > n_rows) rend = n_rows;
    const int start = ptr[r0], end = ptr[rend];
    const int len = end - start;
    const int per = (len + gridDim.y - 1) / gridDim.y;
    const int s0 = start + blockIdx.y * per;
    int s1 = s0 + per; if (s1 > end) s1 = end;
    for (int i = s0 + threadIdx.x; i < s1; i += 256) {
        unsigned pk = recPacked[i];
        int row = r0 + (int)recRow[i];
        int dst = atomicAdd(&rowCur[row], 1);
        edges[dst] = pk;
    }
}

// -------- Pull SpMM: one wave per output row; 4 edges per iteration.
// Lane split: g = lane>>4 selects edge in quad, s = lane&15 covers k = 4s..4s+3.
__global__ __launch_bounds__(256) void pull_spmm(
    const unsigned short* __restrict__ tab0,
    const int* __restrict__ ptr, const unsigned* __restrict__ edges,
    unsigned short* __restrict__ tabF, int S_, int n_rows)
{
    const int w = blockIdx.x * 4 + (threadIdx.x >> 6);
    if (w >= n_rows) return;
    const int lane = threadIdx.x & 63;
    const int g = lane >> 4;
    const int s = lane & 15;

    // student rows gather exercise half (offset S), exercise rows gather student half
    const unsigned short* X = tab0 + ((w < S_) ? ((size_t)S_ << 6) : (size_t)0);

    float4 acc = make_float4(0.f, 0.f, 0.f, 0.f);
    int e = ptr[w], ee = ptr[w + 1];
    while (e < ee) {
        int m = ee - e; if (m > 64) m = 64;
        unsigned u = (lane < m) ? edges[e + lane] : 0u;     // coalesced batch
        int iters = (m + 3) >> 2;
        #pragma unroll 4
        for (int jj = 0; jj < iters; ++jj) {
            unsigned uj = __shfl(u, jj * 4 + g);            // 0-word: col 0, val 0 -> harmless
            float v = __uint_as_float((uj & 0xFFFFu) << 16);
            ushort4 xv = *((const ushort4*)(X + (((size_t)(uj >> 16)) << 6)) + s);
            acc.x = fmaf(v, bf16u_to_f(xv.x), acc.x);
            acc.y = fmaf(v, bf16u_to_f(xv.y), acc.y);
            acc.z = fmaf(v, bf16u_to_f(xv.z), acc.z);
            acc.w = fmaf(v, bf16u_to_f(xv.w), acc.w);
        }
        e += m;
    }

    // combine the 4 edge-groups (lane bits 4,5)
    acc.x += __shfl_xor(acc.x, 16); acc.x += __shfl_xor(acc.x, 32);
    acc.y += __shfl_xor(acc.y, 16); acc.y += __shfl_xor(acc.y, 32);
    acc.z += __shfl_xor(acc.z, 16); acc.z += __shfl_xor(acc.z, 32);
    acc.w += __shfl_xor(acc.w, 16); acc.w += __shfl_xor(acc.w, 32);

    if (g == 0) {
        ushort4 x0v = *((const ushort4*)(tab0 + ((size_t)w << 6)) + s);
        ushort4 o;
        o.x = f_to_bf16u(acc.x + bf16u_to_f(x0v.x));
        o.y = f_to_bf16u(acc.y + bf16u_to_f(x0v.y));
        o.z = f_to_bf16u(acc.z + bf16u_to_f(x0v.z));
        o.w = f_to_bf16u(acc.w + bf16u_to_f(x0v.w));
        *((ushort4*)(tabF + ((size_t)w << 6)) + s) = o;
    }
}

// -------- fused gather + NCD MLP. One block = 64 batch rows. bf16 h-tiles.
__global__ __launch_bounds__(256, 1) void tail_mlp(
    const unsigned short* __restrict__ tabF,
    const float* __restrict__ discW,
    const float* __restrict__ W1, const float* __restrict__ b1,
    const float* __restrict__ W2, const float* __restrict__ b2,
    const float* __restrict__ W3, const float* __restrict__ b3,
    const float* __restrict__ kn, const int* __restrict__ stu_id,
    const int* __restrict__ exer_id, float* __restrict__ out, int S_, int B)
{
    __shared__ float xs[64][64];              // 16 KB
    __shared__ unsigned short h1s[64][256];   // 32 KB (bf16)
    __shared__ unsigned short h2s[64][132];   // 16.5 KB (bf16)
    const int tid = threadIdx.x;
    const int b0 = blockIdx.x * 64;

    for (int i = 0; i < 16; ++i) {
        int e = i * 256 + tid;
        int r = e >> 6, k = e & 63;
        int b = b0 + r;
        float x = 0.f;
        if (b < B) {
            int sid = stu_id[b], eid = exer_id[b];
            float disc = 1.f / (1.f + __expf(-discW[eid]));
            float st = bf16u_to_f(tabF[(size_t)sid * KDIM + k]);
            float df = bf16u_to_f(tabF[(size_t)(S_ + eid) * KDIM + k]);
            x = disc * (st - df) * (1.f / 3.f) * kn[(size_t)b * 64 + k];
        }
        xs[r][k] = x;
    }
    __syncthreads();

    {   // h1 = sigmoid(x @ relu(W1) + b1); thread t owns column t
        float w1c[64];
        #pragma unroll
        for (int k = 0; k < 64; ++k) w1c[k] = fmaxf(W1[k * 256 + tid], 0.f);
        const float bb = b1[tid];
        for (int r = 0; r < 64; ++r) {
            const float4* xr = (const float4*)xs[r];
            float acc = bb;
            #pragma unroll
            for (int k4 = 0; k4 < 16; ++k4) {
                float4 xv = xr[k4];
                acc += xv.x * w1c[k4 * 4 + 0] + xv.y * w1c[k4 * 4 + 1]
                     + xv.z * w1c[k4 * 4 + 2] + xv.w * w1c[k4 * 4 + 3];
            }
            h1s[r][tid] = f_to_bf16u(1.f / (1.f + __expf(-acc)));
        }
    }
    __syncthreads();

    {   // h2 = sigmoid(h1 @ relu(W2) + b2)
        const int j = tid & 127;
        const int rg = tid >> 7;
        float acc3[32];
        #pragma unroll
        for (int r = 0; r < 32; ++r) acc3[r] = b2[j];
        for (int kc = 0; kc < 4; ++kc) {
            float w2c[64];
            #pragma unroll
            for (int i = 0; i < 64; ++i) w2c[i] = fmaxf(W2[(kc * 64 + i) * 128 + j], 0.f);
            #pragma unroll 4
            for (int r = 0; r < 32; ++r) {
                const uint4* hr = (const uint4*)&h1s[rg * 32 + r][kc * 64];
                float a = 0.f;
                #pragma unroll
                for (int i4 = 0; i4 < 8; ++i4) {
                    uint4 hv = hr[i4];
                    a = fmaf(bf16lo(hv.x), w2c[i4 * 8 + 0], a);
                    a = fmaf(bf16hi(hv.x), w2c[i4 * 8 + 1], a);
                    a = fmaf(bf16lo(hv.y), w2c[i4 * 8 + 2], a);
                    a = fmaf(bf16hi(hv.y), w2c[i4 * 8 + 3], a);
                    a = fmaf(bf16lo(hv.z), w2c[i4 * 8 + 4], a);
                    a = fmaf(bf16hi(hv.z), w2c[i4 * 8 + 5], a);
                    a = fmaf(bf16lo(hv.w), w2c[i4 * 8 + 6], a);
                    a = fmaf(bf16hi(hv.w), w2c[i4 * 8 + 7], a);
                }
                acc3[r] += a;
            }
        }
        #pragma unroll
        for (int r = 0; r < 32; ++r)
            h2s[rg * 32 + r][j] = f_to_bf16u(1.f / (1.f + __expf(-acc3[r])));
    }
    __syncthreads();

    if (tid < 64) {
        int b = b0 + tid;
        if (b < B) {
            float acc = b3[0];
            const unsigned* h2r = (const unsigned*)&h2s[tid][0];
            for (int jj = 0; jj < 64; ++jj) {
                unsigned hv = h2r[jj];
                acc += bf16lo(hv) * fmaxf(W3[jj * 2 + 0], 0.f)
                     + bf16hi(hv) * fmaxf(W3[jj * 2 + 1], 0.f);
            }
            out[b] = 1.f / (1.f + __expf(-acc));
        }
    }
}

extern "C" void kernel_launch(void* const* d_in, const int* in_sizes, int n_in,
                              void* d_out, int out_size, void* d_ws, size_t ws_size,
                              hipStream_t stream) {
    const float* stuW  = (const float*)d_in[0];
    const float* exerW = (const float*)d_in[1];
    const float* knowW = (const float*)d_in[2];
    const float* discW = (const float*)d_in[3];
    const float* W1 = (const float*)d_in[4];
    const float* b1 = (const float*)d_in[5];
    const float* W2 = (const float*)d_in[6];
    const float* b2 = (const float*)d_in[7];
    const float* W3 = (const float*)d_in[8];
    const float* b3 = (const float*)d_in[9];
    const int*   ui1_idx = (const int*)d_in[10];
    const float* ui1_val = (const float*)d_in[11];
    const int*   ui0_idx = (const int*)d_in[12];
    const float* ui0_val = (const float*)d_in[13];
    const int*   iu1_idx = (const int*)d_in[14];
    const float* iu1_val = (const float*)d_in[15];
    const int*   iu0_idx = (const int*)d_in[16];
    const float* iu0_val = (const float*)d_in[17];
    const float* kn      = (const float*)d_in[18];
    const int*   stu_id  = (const int*)d_in[19];
    const int*   exer_id = (const int*)d_in[20];
    float* out = (float*)d_out;

    const int S = in_sizes[0] / KDIM;
    const int E = in_sizes[1] / KDIM;
    const int B = in_sizes[19];
    const int n1 = in_sizes[11], n0 = in_sizes[13];
    const int m1 = in_sizes[15], m0 = in_sizes[17];
    const int ntot = n1 + n0 + m1 + m0;
    const int n_rows = S + E;
    const int NB = (n_rows + 255) / 256;            // 274
    const int nb = (n_rows + 1023) / 1024;          // 69
    const int nchunks = (ntot + CHUNK - 1) / CHUNK;

    char* p = (char*)d_ws;
    unsigned short* tab0 = (unsigned short*)p; p += (size_t)n_rows * KDIM * 2;   // 8.96 MB
    unsigned* edges      = (unsigned*)p;       p += (size_t)ntot * 4;            // 16 MB (final)
    unsigned* recPacked  = (unsigned*)p;                                         // 16 MB (temp)
    unsigned short* tabF = (unsigned short*)recPacked;   // aliases recPacked: dead before tabF written
    p += (size_t)ntot * 4;
    unsigned char* recRow = (unsigned char*)p; p += (size_t)ntot;                // 4 MB (temp)
    int* ptr    = (int*)p;                     p += (size_t)(n_rows + 1) * 4;
    int* rowCur = (int*)p;                     p += (size_t)n_rows * 4;
    int* gcurA  = (int*)p;                     p += (size_t)NBPAD * 4;
    int* bsum   = (int*)p;                     p += 1024;

    hipMemsetAsync(rowCur, 0, (size_t)n_rows * 4, stream);

    embed_sig<<<(n_rows + 3) / 4, 256, 0, stream>>>(stuW, exerW, knowW, tab0, S, n_rows);

    row_count<<<(ntot + 255) / 256, 256, 0, stream>>>(ui1_idx, ui0_idx, iu1_idx, iu0_idx,
                                                      n1, n0, m1, S, rowCur, ntot);

    scan_partial<<<nb, 256, 0, stream>>>(rowCur, bsum, n_rows);
    scan_bsum<<<1, 256, 0, stream>>>(bsum, nb, ptr, n_rows);
    scan_final<<<nb, 256, 0, stream>>>(bsum, ptr, rowCur, gcurA, n_rows);

    bin_scatter<<<nchunks, 256, 0, stream>>>(
        ui1_idx, ui1_val, ui0_idx, ui0_val, iu1_idx, iu1_val, iu0_idx, iu0_val,
        n1, n0, m1, m0, S, gcurA, recPacked, recRow, ntot, NB);

    row_sort<<<dim3(NB, 8), 256, 0, stream>>>(recPacked, recRow, ptr, rowCur,
                                              edges, n_rows);

    pull_spmm<<<(n_rows + 3) / 4, 256, 0, stream>>>(tab0, ptr, edges, tabF, S, n_rows);

    tail_mlp<<<(B + 63) / 64, 256, 0, stream>>>(tabF, discW,
                                                W1, b1, W2, b2, W3, b3,
                                                kn, stu_id, exer_id, out, S, B);
}

// Round 6
// 354.888 us; speedup vs baseline: 8.8659x; 1.4909x over previous
//
#include <hip/hip_runtime.h>

#define KDIM 64
#define NBPAD 512          // padded bucket-array size (NB = 274 here)
#define CHUNK 4096         // records per bin_scatter block

__device__ __forceinline__ float bf16u_to_f(unsigned short u) {
    return __uint_as_float(((unsigned)u) << 16);
}
__device__ __forceinline__ float bf16lo(unsigned u) {
    return __uint_as_float(u << 16);
}
__device__ __forceinline__ float bf16hi(unsigned u) {
    return __uint_as_float(u & 0xFFFF0000u);
}
__device__ __forceinline__ unsigned short f_to_bf16u(float f) {
    unsigned b = __float_as_uint(f);
    b += 0x7FFF + ((b >> 16) & 1);          // round-to-nearest-even
    return (unsigned short)(b >> 16);
}

// Unified row space over the 4 concatenated edge lists:
// [0,S) students (ui1,ui0), [S,S+E) exercises (iu1,iu0).
__device__ __forceinline__ int dec_row(int e,
    const int* __restrict__ i1, const int* __restrict__ i0,
    const int* __restrict__ j1, const int* __restrict__ j0,
    int n1, int n0, int m1, int S_)
{
    if (e < n1) return i1[e];
    e -= n1;
    if (e < n0) return i0[e];
    e -= n0;
    if (e < m1) return S_ + j1[e];
    e -= m1;
    return S_ + j0[e];
}

__device__ __forceinline__ void dec_full(int e,
    const int* __restrict__ i1, const float* __restrict__ v1,
    const int* __restrict__ i0, const float* __restrict__ v0,
    const int* __restrict__ j1, const float* __restrict__ w1,
    const int* __restrict__ j0, const float* __restrict__ w0,
    int n1, int n0, int m1, int m0, int S_,
    unsigned& row, unsigned& pk)
{
    int col; float v;
    if (e < n1) { row = (unsigned)i1[e]; col = i1[n1 + e]; v = v1[e]; }
    else if (e < n1 + n0) { int le = e - n1; row = (unsigned)i0[le]; col = i0[n0 + le]; v = v0[le]; }
    else if (e < n1 + n0 + m1) { int le = e - n1 - n0; row = (unsigned)(S_ + j1[le]); col = j1[m1 + le]; v = w1[le]; }
    else { int le = e - n1 - n0 - m1; row = (unsigned)(S_ + j0[le]); col = j0[m0 + le]; v = w0[le]; }
    pk = ((unsigned)col << 16) | (unsigned)f_to_bf16u(v);
}

// -------- Phase 1: tab0[row] = sigmoid(emb_row @ know_W^T)  (unified bf16 table)
__global__ __launch_bounds__(256) void embed_sig(
    const float* __restrict__ stuW, const float* __restrict__ exerW,
    const float* __restrict__ knowW,
    unsigned short* __restrict__ tab0, int S, int n_rows)
{
    __shared__ float kwT[64][65];
    for (int i = threadIdx.x; i < 64 * 64; i += 256) {
        int k = i >> 6, d = i & 63;
        kwT[d][k] = knowW[i];
    }
    __syncthreads();

    const int lane = threadIdx.x & 63;
    const int row = blockIdx.x * 4 + (threadIdx.x >> 6);
    if (row >= n_rows) return;
    const float* a = (row < S) ? (stuW + (size_t)row * KDIM)
                               : (exerW + (size_t)(row - S) * KDIM);
    const float4* a4 = (const float4*)a;
    float acc = 0.f;
    #pragma unroll
    for (int d4 = 0; d4 < 16; ++d4) {
        float4 av = a4[d4];
        acc += av.x * kwT[d4 * 4 + 0][lane];
        acc += av.y * kwT[d4 * 4 + 1][lane];
        acc += av.z * kwT[d4 * 4 + 2][lane];
        acc += av.w * kwT[d4 * 4 + 3][lane];
    }
    float s = 1.f / (1.f + __expf(-acc));
    tab0[(size_t)row * KDIM + lane] = f_to_bf16u(s);
}

// -------- bucket histogram: LDS-aggregated, few global atomics (274 counters)
__global__ __launch_bounds__(256) void bucket_count(
    const int* __restrict__ i1, const int* __restrict__ i0,
    const int* __restrict__ j1, const int* __restrict__ j0,
    int n1, int n0, int m1, int S_,
    int* __restrict__ bktCnt, int ntot, int NB)
{
    __shared__ int h[NBPAD];
    for (int i = threadIdx.x; i < NBPAD; i += 256) h[i] = 0;
    __syncthreads();
    const int e0 = blockIdx.x * CHUNK;
    #pragma unroll
    for (int it = 0; it < 16; ++it) {
        int e = e0 + it * 256 + threadIdx.x;
        if (e < ntot) atomicAdd(&h[dec_row(e, i1, i0, j1, j0, n1, n0, m1, S_) >> 8], 1);
    }
    __syncthreads();
    for (int b = threadIdx.x; b < NB; b += 256)
        if (h[b]) atomicAdd(&bktCnt[b], h[b]);
}

// -------- exclusive scan of NB bucket counts -> bktBase (+ cursor copy gcurA)
__global__ __launch_bounds__(256) void scan_tiny(
    const int* __restrict__ bktCnt, int* __restrict__ bktBase,
    int* __restrict__ gcurA, int NB)
{
    __shared__ int s[NBPAD + 1];
    for (int i = threadIdx.x; i < NB; i += 256) s[i] = bktCnt[i];
    __syncthreads();
    if (threadIdx.x == 0) {
        int acc = 0;
        for (int b = 0; b < NB; ++b) { int c = s[b]; s[b] = acc; acc += c; }
        s[NB] = acc;
    }
    __syncthreads();
    for (int i = threadIdx.x; i <= NB; i += 256) bktBase[i] = s[i];
    for (int i = threadIdx.x; i < NB; i += 256) gcurA[i] = s[i];
}

// -------- binned scatter: LDS reorder by 256-row bucket, drain coalesced runs.
__global__ __launch_bounds__(256) void bin_scatter(
    const int* __restrict__ i1, const float* __restrict__ v1,
    const int* __restrict__ i0, const float* __restrict__ v0,
    const int* __restrict__ j1, const float* __restrict__ w1,
    const int* __restrict__ j0, const float* __restrict__ w0,
    int n1, int n0, int m1, int m0, int S_,
    int* __restrict__ gcurA,
    unsigned* __restrict__ recPacked, unsigned char* __restrict__ recRow,
    int ntot, int NB)
{
    __shared__ int h[NBPAD], sstart[NBPAD], lbase[NBPAD], gdst[NBPAD];
    __shared__ unsigned stageP[CHUNK];
    __shared__ unsigned char stageR[CHUNK];
    __shared__ unsigned short stageB[CHUNK];
    const int tid = threadIdx.x;
    const int e0 = blockIdx.x * CHUNK;

    for (int i = tid; i < NBPAD; i += 256) h[i] = 0;
    __syncthreads();

    unsigned rrow[16], rpk[16];
    #pragma unroll
    for (int it = 0; it < 16; ++it) {
        int e = e0 + it * 256 + tid;
        if (e < ntot) {
            dec_full(e, i1, v1, i0, v0, j1, w1, j0, w0, n1, n0, m1, m0, S_,
                     rrow[it], rpk[it]);
            atomicAdd(&h[rrow[it] >> 8], 1);
        } else {
            rrow[it] = 0xFFFFFFFFu;
        }
    }
    __syncthreads();

    {   // exclusive prefix over NB buckets; thread t owns buckets t and t+256
        int acc0 = 0, acc1 = 0;
        for (int b = 0; b < NB; ++b) {
            int hv = h[b];
            if (b < tid)       acc0 += hv;
            if (b < tid + 256) acc1 += hv;
        }
        sstart[tid] = acc0; lbase[tid] = acc0;
        int c0 = h[tid];
        if (c0 > 0) gdst[tid] = atomicAdd(&gcurA[tid], c0);
        if (tid + 256 < NB) {
            sstart[tid + 256] = acc1; lbase[tid + 256] = acc1;
            int c1 = h[tid + 256];
            if (c1 > 0) gdst[tid + 256] = atomicAdd(&gcurA[tid + 256], c1);
        }
    }
    __syncthreads();

    #pragma unroll
    for (int it = 0; it < 16; ++it) {
        if (rrow[it] != 0xFFFFFFFFu) {
            int bkt = rrow[it] >> 8;
            int slot = atomicAdd(&lbase[bkt], 1);
            stageP[slot] = rpk[it];
            stageR[slot] = (unsigned char)(rrow[it] & 255u);
            stageB[slot] = (unsigned short)bkt;
        }
    }
    __syncthreads();

    int cnt = ntot - e0; if (cnt > CHUNK) cnt = CHUNK;
    for (int i = tid; i < cnt; i += 256) {
        int bkt = stageB[i];
        int dst = gdst[bkt] + (i - sstart[bkt]);
        recPacked[dst] = stageP[i];
        recRow[dst]   = stageR[i];
    }
}

// -------- per-bucket row sort WITH built-in per-row histogram + scan + ptr emit.
// grid (NB, 2): each y-block scatters half the bucket's records; both y-blocks
// histogram BOTH halves (recRow is 1 B/record) so half-1 gets disjoint slot
// bases (excl[r] + h0[r]) -> deterministic, no global per-row atomics at all.
__global__ __launch_bounds__(256) void row_sort(
    const unsigned* __restrict__ recPacked, const unsigned char* __restrict__ recRow,
    const int* __restrict__ bktBase,
    int* __restrict__ ptr, unsigned* __restrict__ edges, int n_rows, int NB)
{
    __shared__ int h0[256], h1[256], sc[256], cur[256];
    const int b = blockIdx.x;
    const int half = blockIdx.y;
    const int tid = threadIdx.x;
    const int r0 = b << 8;
    const int start = bktBase[b], end = bktBase[b + 1];
    const int mid = start + ((end - start) >> 1);

    h0[tid] = 0; h1[tid] = 0;
    __syncthreads();

    for (int i = start + tid; i < end; i += 256) {
        int r = (int)recRow[i];
        if (i < mid) atomicAdd(&h0[r], 1);
        else         atomicAdd(&h1[r], 1);
    }
    __syncthreads();

    const int tot = h0[tid] + h1[tid];
    sc[tid] = tot;
    __syncthreads();
    for (int o = 1; o < 256; o <<= 1) {
        int add = (tid >= o) ? sc[tid - o] : 0;
        __syncthreads();
        sc[tid] += add;
        __syncthreads();
    }
    const int excl = sc[tid] - tot;

    if (half == 0) {
        int grow = r0 + tid;
        if (grow < n_rows) ptr[grow] = start + excl;
        if (b == NB - 1 && tid == 0) ptr[n_rows] = end;
    }
    cur[tid] = excl + (half ? h0[tid] : 0);
    __syncthreads();

    const int s0 = half ? mid : start;
    const int s1 = half ? end : mid;
    for (int i = s0 + tid; i < s1; i += 256) {
        unsigned pk = recPacked[i];
        int r = (int)recRow[i];
        int dst = start + atomicAdd(&cur[r], 1);
        edges[dst] = pk;
    }
}

// -------- Pull SpMM: one wave per output row; 4 edges per iteration; batch
// prefetch of the next 64 records overlaps the 16 shfl/gather steps.
__global__ __launch_bounds__(256) void pull_spmm(
    const unsigned short* __restrict__ tab0,
    const int* __restrict__ ptr, const unsigned* __restrict__ edges,
    unsigned short* __restrict__ tabF, int S_, int n_rows)
{
    const int w = blockIdx.x * 4 + (threadIdx.x >> 6);
    if (w >= n_rows) return;
    const int lane = threadIdx.x & 63;
    const int g = lane >> 4;
    const int s = lane & 15;

    // student rows gather exercise half (offset S), exercise rows gather student half
    const unsigned short* X = tab0 + ((w < S_) ? ((size_t)S_ << 6) : (size_t)0);

    float4 acc = make_float4(0.f, 0.f, 0.f, 0.f);
    int e = ptr[w];
    const int ee = ptr[w + 1];
    unsigned u = (e + lane < ee) ? edges[e + lane] : 0u;
    while (e < ee) {
        int m = ee - e; if (m > 64) m = 64;
        unsigned un = (e + 64 + lane < ee) ? edges[e + 64 + lane] : 0u;  // prefetch
        int iters = (m + 3) >> 2;
        #pragma unroll 4
        for (int jj = 0; jj < iters; ++jj) {
            unsigned uj = __shfl(u, jj * 4 + g);            // 0-word: col 0, val 0 -> harmless
            float v = __uint_as_float((uj & 0xFFFFu) << 16);
            ushort4 xv = *((const ushort4*)(X + (((size_t)(uj >> 16)) << 6)) + s);
            acc.x = fmaf(v, bf16u_to_f(xv.x), acc.x);
            acc.y = fmaf(v, bf16u_to_f(xv.y), acc.y);
            acc.z = fmaf(v, bf16u_to_f(xv.z), acc.z);
            acc.w = fmaf(v, bf16u_to_f(xv.w), acc.w);
        }
        u = un;
        e += m;
    }

    // combine the 4 edge-groups (lane bits 4,5)
    acc.x += __shfl_xor(acc.x, 16); acc.x += __shfl_xor(acc.x, 32);
    acc.y += __shfl_xor(acc.y, 16); acc.y += __shfl_xor(acc.y, 32);
    acc.z += __shfl_xor(acc.z, 16); acc.z += __shfl_xor(acc.z, 32);
    acc.w += __shfl_xor(acc.w, 16); acc.w += __shfl_xor(acc.w, 32);

    if (g == 0) {
        ushort4 x0v = *((const ushort4*)(tab0 + ((size_t)w << 6)) + s);
        ushort4 o;
        o.x = f_to_bf16u(acc.x + bf16u_to_f(x0v.x));
        o.y = f_to_bf16u(acc.y + bf16u_to_f(x0v.y));
        o.z = f_to_bf16u(acc.z + bf16u_to_f(x0v.z));
        o.w = f_to_bf16u(acc.w + bf16u_to_f(x0v.w));
        *((ushort4*)(tabF + ((size_t)w << 6)) + s) = o;
    }
}

// -------- fused gather + NCD MLP. One block = 64 batch rows. bf16 h-tiles.
__global__ __launch_bounds__(256, 1) void tail_mlp(
    const unsigned short* __restrict__ tabF,
    const float* __restrict__ discW,
    const float* __restrict__ W1, const float* __restrict__ b1,
    const float* __restrict__ W2, const float* __restrict__ b2,
    const float* __restrict__ W3, const float* __restrict__ b3,
    const float* __restrict__ kn, const int* __restrict__ stu_id,
    const int* __restrict__ exer_id, float* __restrict__ out, int S_, int B)
{
    __shared__ float xs[64][64];              // 16 KB
    __shared__ unsigned short h1s[64][256];   // 32 KB (bf16)
    __shared__ unsigned short h2s[64][132];   // 16.5 KB (bf16)
    const int tid = threadIdx.x;
    const int b0 = blockIdx.x * 64;

    for (int i = 0; i < 16; ++i) {
        int e = i * 256 + tid;
        int r = e >> 6, k = e & 63;
        int b = b0 + r;
        float x = 0.f;
        if (b < B) {
            int sid = stu_id[b], eid = exer_id[b];
            float disc = 1.f / (1.f + __expf(-discW[eid]));
            float st = bf16u_to_f(tabF[(size_t)sid * KDIM + k]);
            float df = bf16u_to_f(tabF[(size_t)(S_ + eid) * KDIM + k]);
            x = disc * (st - df) * (1.f / 3.f) * kn[(size_t)b * 64 + k];
        }
        xs[r][k] = x;
    }
    __syncthreads();

    {   // h1 = sigmoid(x @ relu(W1) + b1); thread t owns column t
        float w1c[64];
        #pragma unroll
        for (int k = 0; k < 64; ++k) w1c[k] = fmaxf(W1[k * 256 + tid], 0.f);
        const float bb = b1[tid];
        for (int r = 0; r < 64; ++r) {
            const float4* xr = (const float4*)xs[r];
            float acc = bb;
            #pragma unroll
            for (int k4 = 0; k4 < 16; ++k4) {
                float4 xv = xr[k4];
                acc += xv.x * w1c[k4 * 4 + 0] + xv.y * w1c[k4 * 4 + 1]
                     + xv.z * w1c[k4 * 4 + 2] + xv.w * w1c[k4 * 4 + 3];
            }
            h1s[r][tid] = f_to_bf16u(1.f / (1.f + __expf(-acc)));
        }
    }
    __syncthreads();

    {   // h2 = sigmoid(h1 @ relu(W2) + b2)
        const int j = tid & 127;
        const int rg = tid >> 7;
        float acc3[32];
        #pragma unroll
        for (int r = 0; r < 32; ++r) acc3[r] = b2[j];
        for (int kc = 0; kc < 4; ++kc) {
            float w2c[64];
            #pragma unroll
            for (int i = 0; i < 64; ++i) w2c[i] = fmaxf(W2[(kc * 64 + i) * 128 + j], 0.f);
            #pragma unroll 4
            for (int r = 0; r < 32; ++r) {
                const uint4* hr = (const uint4*)&h1s[rg * 32 + r][kc * 64];
                float a = 0.f;
                #pragma unroll
                for (int i4 = 0; i4 < 8; ++i4) {
                    uint4 hv = hr[i4];
                    a = fmaf(bf16lo(hv.x), w2c[i4 * 8 + 0], a);
                    a = fmaf(bf16hi(hv.x), w2c[i4 * 8 + 1], a);
                    a = fmaf(bf16lo(hv.y), w2c[i4 * 8 + 2], a);
                    a = fmaf(bf16hi(hv.y), w2c[i4 * 8 + 3], a);
                    a = fmaf(bf16lo(hv.z), w2c[i4 * 8 + 4], a);
                    a = fmaf(bf16hi(hv.z), w2c[i4 * 8 + 5], a);
                    a = fmaf(bf16lo(hv.w), w2c[i4 * 8 + 6], a);
                    a = fmaf(bf16hi(hv.w), w2c[i4 * 8 + 7], a);
                }
                acc3[r] += a;
            }
        }
        #pragma unroll
        for (int r = 0; r < 32; ++r)
            h2s[rg * 32 + r][j] = f_to_bf16u(1.f / (1.f + __expf(-acc3[r])));
    }
    __syncthreads();

    if (tid < 64) {
        int b = b0 + tid;
        if (b < B) {
            float acc = b3[0];
            const unsigned* h2r = (const unsigned*)&h2s[tid][0];
            for (int jj = 0; jj < 64; ++jj) {
                unsigned hv = h2r[jj];
                acc += bf16lo(hv) * fmaxf(W3[jj * 2 + 0], 0.f)
                     + bf16hi(hv) * fmaxf(W3[jj * 2 + 1], 0.f);
            }
            out[b] = 1.f / (1.f + __expf(-acc));
        }
    }
}

extern "C" void kernel_launch(void* const* d_in, const int* in_sizes, int n_in,
                              void* d_out, int out_size, void* d_ws, size_t ws_size,
                              hipStream_t stream) {
    const float* stuW  = (const float*)d_in[0];
    const float* exerW = (const float*)d_in[1];
    const float* knowW = (const float*)d_in[2];
    const float* discW = (const float*)d_in[3];
    const float* W1 = (const float*)d_in[4];
    const float* b1 = (const float*)d_in[5];
    const float* W2 = (const float*)d_in[6];
    const float* b2 = (const float*)d_in[7];
    const float* W3 = (const float*)d_in[8];
    const float* b3 = (const float*)d_in[9];
    const int*   ui1_idx = (const int*)d_in[10];
    const float* ui1_val = (const float*)d_in[11];
    const int*   ui0_idx = (const int*)d_in[12];
    const float* ui0_val = (const float*)d_in[13];
    const int*   iu1_idx = (const int*)d_in[14];
    const float* iu1_val = (const float*)d_in[15];
    const int*   iu0_idx = (const int*)d_in[16];
    const float* iu0_val = (const float*)d_in[17];
    const float* kn      = (const float*)d_in[18];
    const int*   stu_id  = (const int*)d_in[19];
    const int*   exer_id = (const int*)d_in[20];
    float* out = (float*)d_out;

    const int S = in_sizes[0] / KDIM;
    const int E = in_sizes[1] / KDIM;
    const int B = in_sizes[19];
    const int n1 = in_sizes[11], n0 = in_sizes[13];
    const int m1 = in_sizes[15], m0 = in_sizes[17];
    const int ntot = n1 + n0 + m1 + m0;
    const int n_rows = S + E;
    const int NB = (n_rows + 255) / 256;            // 274
    const int nchunks = (ntot + CHUNK - 1) / CHUNK;

    char* p = (char*)d_ws;
    unsigned short* tab0 = (unsigned short*)p; p += (size_t)n_rows * KDIM * 2;   // 8.96 MB
    unsigned* edges      = (unsigned*)p;       p += (size_t)ntot * 4;            // 16 MB (final)
    unsigned* recPacked  = (unsigned*)p;                                         // 16 MB (temp)
    unsigned short* tabF = (unsigned short*)recPacked;   // aliases recPacked: dead before tabF written
    p += (size_t)ntot * 4;
    unsigned char* recRow = (unsigned char*)p; p += (size_t)ntot;                // 4 MB (temp)
    int* ptr    = (int*)p;                     p += (size_t)(n_rows + 1) * 4;
    int* bktCnt = (int*)p;                     p += (size_t)NBPAD * 4;
    int* bktBase= (int*)p;                     p += (size_t)(NBPAD + 1) * 4;
    int* gcurA  = (int*)p;                     p += (size_t)NBPAD * 4;

    hipMemsetAsync(bktCnt, 0, (size_t)NB * 4, stream);

    embed_sig<<<(n_rows + 3) / 4, 256, 0, stream>>>(stuW, exerW, knowW, tab0, S, n_rows);

    bucket_count<<<nchunks, 256, 0, stream>>>(ui1_idx, ui0_idx, iu1_idx, iu0_idx,
                                              n1, n0, m1, S, bktCnt, ntot, NB);

    scan_tiny<<<1, 256, 0, stream>>>(bktCnt, bktBase, gcurA, NB);

    bin_scatter<<<nchunks, 256, 0, stream>>>(
        ui1_idx, ui1_val, ui0_idx, ui0_val, iu1_idx, iu1_val, iu0_idx, iu0_val,
        n1, n0, m1, m0, S, gcurA, recPacked, recRow, ntot, NB);

    row_sort<<<dim3(NB, 2), 256, 0, stream>>>(recPacked, recRow, bktBase,
                                              ptr, edges, n_rows, NB);

    pull_spmm<<<(n_rows + 3) / 4, 256, 0, stream>>>(tab0, ptr, edges, tabF, S, n_rows);

    tail_mlp<<<(B + 63) / 64, 256, 0, stream>>>(tabF, discW,
                                                W1, b1, W2, b2, W3, b3,
                                                kn, stu_id, exer_id, out, S, B);
}

// Round 7
// 300.339 us; speedup vs baseline: 10.4762x; 1.1816x over previous
//
#include <hip/hip_runtime.h>

#define KDIM 64
#define NBPAD 512          // padded bucket-array size (NB = 274 here)
#define CHUNK 4096         // records per bin_scatter block

typedef __attribute__((ext_vector_type(8))) short short8v;   // 8 bf16 (4 VGPRs)
typedef __attribute__((ext_vector_type(4))) float f32x4;     // MFMA acc

__device__ __forceinline__ float bf16u_to_f(unsigned short u) {
    return __uint_as_float(((unsigned)u) << 16);
}
__device__ __forceinline__ float bf16lo(unsigned u) {
    return __uint_as_float(u << 16);
}
__device__ __forceinline__ float bf16hi(unsigned u) {
    return __uint_as_float(u & 0xFFFF0000u);
}
__device__ __forceinline__ unsigned short f_to_bf16u(float f) {
    unsigned b = __float_as_uint(f);
    b += 0x7FFF + ((b >> 16) & 1);          // round-to-nearest-even
    return (unsigned short)(b >> 16);
}
__device__ __forceinline__ float sigmoidf_(float x) {
    return 1.f / (1.f + __expf(-x));
}

// Unified row space over the 4 concatenated edge lists:
// [0,S) students (ui1,ui0), [S,S+E) exercises (iu1,iu0).
__device__ __forceinline__ int dec_row(int e,
    const int* __restrict__ i1, const int* __restrict__ i0,
    const int* __restrict__ j1, const int* __restrict__ j0,
    int n1, int n0, int m1, int S_)
{
    if (e < n1) return i1[e];
    e -= n1;
    if (e < n0) return i0[e];
    e -= n0;
    if (e < m1) return S_ + j1[e];
    e -= m1;
    return S_ + j0[e];
}

__device__ __forceinline__ void dec_full(int e,
    const int* __restrict__ i1, const float* __restrict__ v1,
    const int* __restrict__ i0, const float* __restrict__ v0,
    const int* __restrict__ j1, const float* __restrict__ w1,
    const int* __restrict__ j0, const float* __restrict__ w0,
    int n1, int n0, int m1, int m0, int S_,
    unsigned& row, unsigned& pk)
{
    int col; float v;
    if (e < n1) { row = (unsigned)i1[e]; col = i1[n1 + e]; v = v1[e]; }
    else if (e < n1 + n0) { int le = e - n1; row = (unsigned)i0[le]; col = i0[n0 + le]; v = v0[le]; }
    else if (e < n1 + n0 + m1) { int le = e - n1 - n0; row = (unsigned)(S_ + j1[le]); col = j1[m1 + le]; v = w1[le]; }
    else { int le = e - n1 - n0 - m1; row = (unsigned)(S_ + j0[le]); col = j0[m0 + le]; v = w0[le]; }
    pk = ((unsigned)col << 16) | (unsigned)f_to_bf16u(v);
}

// -------- Phase 1: tab0[row] = sigmoid(emb_row @ know_W^T)  (unified bf16 table)
__global__ __launch_bounds__(256) void embed_sig(
    const float* __restrict__ stuW, const float* __restrict__ exerW,
    const float* __restrict__ knowW,
    unsigned short* __restrict__ tab0, int S, int n_rows)
{
    __shared__ float kwT[64][65];
    for (int i = threadIdx.x; i < 64 * 64; i += 256) {
        int k = i >> 6, d = i & 63;
        kwT[d][k] = knowW[i];
    }
    __syncthreads();

    const int lane = threadIdx.x & 63;
    const int row = blockIdx.x * 4 + (threadIdx.x >> 6);
    if (row >= n_rows) return;
    const float* a = (row < S) ? (stuW + (size_t)row * KDIM)
                               : (exerW + (size_t)(row - S) * KDIM);
    const float4* a4 = (const float4*)a;
    float acc = 0.f;
    #pragma unroll
    for (int d4 = 0; d4 < 16; ++d4) {
        float4 av = a4[d4];
        acc += av.x * kwT[d4 * 4 + 0][lane];
        acc += av.y * kwT[d4 * 4 + 1][lane];
        acc += av.z * kwT[d4 * 4 + 2][lane];
        acc += av.w * kwT[d4 * 4 + 3][lane];
    }
    tab0[(size_t)row * KDIM + lane] = f_to_bf16u(sigmoidf_(acc));
}

// -------- weight prep: relu + transpose + bf16 (W1t[256n][64k], W2t[128n][256k], w3r)
__global__ __launch_bounds__(256) void prep_w(
    const float* __restrict__ W1, const float* __restrict__ W2,
    const float* __restrict__ W3,
    unsigned short* __restrict__ W1t, unsigned short* __restrict__ W2t,
    float* __restrict__ w3r)
{
    int i = blockIdx.x * 256 + threadIdx.x;
    if (i < 256 * 64) {                     // W1t[n][k] = relu(W1[k][n])
        int n = i >> 6, k = i & 63;
        W1t[i] = f_to_bf16u(fmaxf(W1[k * 256 + n], 0.f));
        return;
    }
    int j = i - 256 * 64;
    if (j < 128 * 256) {                    // W2t[n][k] = relu(W2[k][n])
        int n = j >> 8, k = j & 255;
        W2t[j] = f_to_bf16u(fmaxf(W2[k * 128 + n], 0.f));
        return;
    }
    int l = j - 128 * 256;
    if (l < 128) w3r[l] = fmaxf(W3[l], 0.f);
}

// -------- bucket histogram: LDS-aggregated, few global atomics (274 counters)
__global__ __launch_bounds__(256) void bucket_count(
    const int* __restrict__ i1, const int* __restrict__ i0,
    const int* __restrict__ j1, const int* __restrict__ j0,
    int n1, int n0, int m1, int S_,
    int* __restrict__ bktCnt, int ntot, int NB)
{
    __shared__ int h[NBPAD];
    for (int i = threadIdx.x; i < NBPAD; i += 256) h[i] = 0;
    __syncthreads();
    const int e0 = blockIdx.x * CHUNK;
    #pragma unroll
    for (int it = 0; it < 16; ++it) {
        int e = e0 + it * 256 + threadIdx.x;
        if (e < ntot) atomicAdd(&h[dec_row(e, i1, i0, j1, j0, n1, n0, m1, S_) >> 8], 1);
    }
    __syncthreads();
    for (int b = threadIdx.x; b < NB; b += 256)
        if (h[b]) atomicAdd(&bktCnt[b], h[b]);
}

// -------- exclusive scan of NB bucket counts -> bktBase (+ cursor copy gcurA)
__global__ __launch_bounds__(256) void scan_tiny(
    const int* __restrict__ bktCnt, int* __restrict__ bktBase,
    int* __restrict__ gcurA, int NB)
{
    __shared__ int s[NBPAD + 1];
    for (int i = threadIdx.x; i < NB; i += 256) s[i] = bktCnt[i];
    __syncthreads();
    if (threadIdx.x == 0) {
        int acc = 0;
        for (int b = 0; b < NB; ++b) { int c = s[b]; s[b] = acc; acc += c; }
        s[NB] = acc;
    }
    __syncthreads();
    for (int i = threadIdx.x; i <= NB; i += 256) bktBase[i] = s[i];
    for (int i = threadIdx.x; i < NB; i += 256) gcurA[i] = s[i];
}

// -------- binned scatter: LDS reorder by 256-row bucket, drain coalesced runs.
__global__ __launch_bounds__(256) void bin_scatter(
    const int* __restrict__ i1, const float* __restrict__ v1,
    const int* __restrict__ i0, const float* __restrict__ v0,
    const int* __restrict__ j1, const float* __restrict__ w1,
    const int* __restrict__ j0, const float* __restrict__ w0,
    int n1, int n0, int m1, int m0, int S_,
    int* __restrict__ gcurA,
    unsigned* __restrict__ recPacked, unsigned char* __restrict__ recRow,
    int ntot, int NB)
{
    __shared__ int h[NBPAD], sstart[NBPAD], lbase[NBPAD], gdst[NBPAD];
    __shared__ unsigned stageP[CHUNK];
    __shared__ unsigned char stageR[CHUNK];
    __shared__ unsigned short stageB[CHUNK];
    const int tid = threadIdx.x;
    const int e0 = blockIdx.x * CHUNK;

    for (int i = tid; i < NBPAD; i += 256) h[i] = 0;
    __syncthreads();

    unsigned rrow[16], rpk[16];
    #pragma unroll
    for (int it = 0; it < 16; ++it) {
        int e = e0 + it * 256 + tid;
        if (e < ntot) {
            dec_full(e, i1, v1, i0, v0, j1, w1, j0, w0, n1, n0, m1, m0, S_,
                     rrow[it], rpk[it]);
            atomicAdd(&h[rrow[it] >> 8], 1);
        } else {
            rrow[it] = 0xFFFFFFFFu;
        }
    }
    __syncthreads();

    {   // exclusive prefix over NB buckets; thread t owns buckets t and t+256
        int acc0 = 0, acc1 = 0;
        for (int b = 0; b < NB; ++b) {
            int hv = h[b];
            if (b < tid)       acc0 += hv;
            if (b < tid + 256) acc1 += hv;
        }
        sstart[tid] = acc0; lbase[tid] = acc0;
        int c0 = h[tid];
        if (c0 > 0) gdst[tid] = atomicAdd(&gcurA[tid], c0);
        if (tid + 256 < NB) {
            sstart[tid + 256] = acc1; lbase[tid + 256] = acc1;
            int c1 = h[tid + 256];
            if (c1 > 0) gdst[tid + 256] = atomicAdd(&gcurA[tid + 256], c1);
        }
    }
    __syncthreads();

    #pragma unroll
    for (int it = 0; it < 16; ++it) {
        if (rrow[it] != 0xFFFFFFFFu) {
            int bkt = rrow[it] >> 8;
            int slot = atomicAdd(&lbase[bkt], 1);
            stageP[slot] = rpk[it];
            stageR[slot] = (unsigned char)(rrow[it] & 255u);
            stageB[slot] = (unsigned short)bkt;
        }
    }
    __syncthreads();

    int cnt = ntot - e0; if (cnt > CHUNK) cnt = CHUNK;
    for (int i = tid; i < cnt; i += 256) {
        int bkt = stageB[i];
        int dst = gdst[bkt] + (i - sstart[bkt]);
        recPacked[dst] = stageP[i];
        recRow[dst]   = stageR[i];
    }
}

// -------- per-bucket row sort WITH built-in per-row histogram + scan + ptr emit.
__global__ __launch_bounds__(256) void row_sort(
    const unsigned* __restrict__ recPacked, const unsigned char* __restrict__ recRow,
    const int* __restrict__ bktBase,
    int* __restrict__ ptr, unsigned* __restrict__ edges, int n_rows, int NB)
{
    __shared__ int h0[256], h1[256], sc[256], cur[256];
    const int b = blockIdx.x;
    const int half = blockIdx.y;
    const int tid = threadIdx.x;
    const int r0 = b << 8;
    const int start = bktBase[b], end = bktBase[b + 1];
    const int mid = start + ((end - start) >> 1);

    h0[tid] = 0; h1[tid] = 0;
    __syncthreads();

    for (int i = start + tid; i < end; i += 256) {
        int r = (int)recRow[i];
        if (i < mid) atomicAdd(&h0[r], 1);
        else         atomicAdd(&h1[r], 1);
    }
    __syncthreads();

    const int tot = h0[tid] + h1[tid];
    sc[tid] = tot;
    __syncthreads();
    for (int o = 1; o < 256; o <<= 1) {
        int add = (tid >= o) ? sc[tid - o] : 0;
        __syncthreads();
        sc[tid] += add;
        __syncthreads();
    }
    const int excl = sc[tid] - tot;

    if (half == 0) {
        int grow = r0 + tid;
        if (grow < n_rows) ptr[grow] = start + excl;
        if (b == NB - 1 && tid == 0) ptr[n_rows] = end;
    }
    cur[tid] = excl + (half ? h0[tid] : 0);
    __syncthreads();

    const int s0 = half ? mid : start;
    const int s1 = half ? end : mid;
    for (int i = s0 + tid; i < s1; i += 256) {
        unsigned pk = recPacked[i];
        int r = (int)recRow[i];
        int dst = start + atomicAdd(&cur[r], 1);
        edges[dst] = pk;
    }
}

// -------- Pull SpMM: one wave per output row; 4 edges per iteration; prefetch.
__global__ __launch_bounds__(256) void pull_spmm(
    const unsigned short* __restrict__ tab0,
    const int* __restrict__ ptr, const unsigned* __restrict__ edges,
    unsigned short* __restrict__ tabF, int S_, int n_rows)
{
    const int w = blockIdx.x * 4 + (threadIdx.x >> 6);
    if (w >= n_rows) return;
    const int lane = threadIdx.x & 63;
    const int g = lane >> 4;
    const int s = lane & 15;

    const unsigned short* X = tab0 + ((w < S_) ? ((size_t)S_ << 6) : (size_t)0);

    float4 acc = make_float4(0.f, 0.f, 0.f, 0.f);
    int e = ptr[w];
    const int ee = ptr[w + 1];
    unsigned u = (e + lane < ee) ? edges[e + lane] : 0u;
    while (e < ee) {
        int m = ee - e; if (m > 64) m = 64;
        unsigned un = (e + 64 + lane < ee) ? edges[e + 64 + lane] : 0u;  // prefetch
        int iters = (m + 3) >> 2;
        #pragma unroll 4
        for (int jj = 0; jj < iters; ++jj) {
            unsigned uj = __shfl(u, jj * 4 + g);
            float v = __uint_as_float((uj & 0xFFFFu) << 16);
            ushort4 xv = *((const ushort4*)(X + (((size_t)(uj >> 16)) << 6)) + s);
            acc.x = fmaf(v, bf16u_to_f(xv.x), acc.x);
            acc.y = fmaf(v, bf16u_to_f(xv.y), acc.y);
            acc.z = fmaf(v, bf16u_to_f(xv.z), acc.z);
            acc.w = fmaf(v, bf16u_to_f(xv.w), acc.w);
        }
        u = un;
        e += m;
    }

    acc.x += __shfl_xor(acc.x, 16); acc.x += __shfl_xor(acc.x, 32);
    acc.y += __shfl_xor(acc.y, 16); acc.y += __shfl_xor(acc.y, 32);
    acc.z += __shfl_xor(acc.z, 16); acc.z += __shfl_xor(acc.z, 32);
    acc.w += __shfl_xor(acc.w, 16); acc.w += __shfl_xor(acc.w, 32);

    if (g == 0) {
        ushort4 x0v = *((const ushort4*)(tab0 + ((size_t)w << 6)) + s);
        ushort4 o;
        o.x = f_to_bf16u(acc.x + bf16u_to_f(x0v.x));
        o.y = f_to_bf16u(acc.y + bf16u_to_f(x0v.y));
        o.z = f_to_bf16u(acc.z + bf16u_to_f(x0v.z));
        o.w = f_to_bf16u(acc.w + bf16u_to_f(x0v.w));
        *((ushort4*)(tabF + ((size_t)w << 6)) + s) = o;
    }
}

// -------- MFMA tail: gather -> GEMM1(64x256x64) -> GEMM2(64x128x256) -> dot.
// One block = 64 batch rows, 4 waves; wave w owns rows 16w..16w+15.
// Fragment layouts (gfx950 16x16x32 bf16): A: row=l&15, k=(l>>4)*8+j (8 contig);
// B: col=l&15, k=(l>>4)*8+j (8 contig in W^T layout); C: col=l&15, row=(l>>4)*4+q.
__global__ __launch_bounds__(256) void tail_mlp(
    const unsigned short* __restrict__ tabF,
    const float* __restrict__ discW,
    const unsigned short* __restrict__ W1t, const float* __restrict__ b1,
    const unsigned short* __restrict__ W2t, const float* __restrict__ b2,
    const float* __restrict__ w3r, const float* __restrict__ b3,
    const float* __restrict__ kn, const int* __restrict__ stu_id,
    const int* __restrict__ exer_id, float* __restrict__ out, int S_, int B)
{
    __shared__ __align__(16) unsigned short xs_bf[64][72];   // 9.0 KB (pad: 2-way banks)
    __shared__ __align__(16) unsigned short h1s[64][264];    // 33.0 KB
    __shared__ __align__(16) unsigned short h2s[64][136];    // 17.0 KB
    __shared__ float b1s[256], b2s[128], w3s[128];
    const int tid = threadIdx.x;
    const int b0 = blockIdx.x * 64;

    b1s[tid] = b1[tid];
    if (tid < 128) { b2s[tid] = b2[tid]; w3s[tid] = w3r[tid]; }

    // ---- phase 0: x = disc*(stat-diff)/3*kn -> bf16 LDS tile (vectorized x4)
    #pragma unroll
    for (int i = 0; i < 4; ++i) {
        int e4 = (i * 256 + tid) * 4;
        int r = e4 >> 6, k0 = e4 & 63;
        int b = b0 + r;
        float4 x4 = make_float4(0.f, 0.f, 0.f, 0.f);
        if (b < B) {
            int sid = stu_id[b], eid = exer_id[b];
            float c = sigmoidf_(discW[eid]) * (1.f / 3.f);
            ushort4 st4 = *((const ushort4*)(tabF + (size_t)sid * 64 + k0));
            ushort4 df4 = *((const ushort4*)(tabF + ((size_t)(S_ + eid)) * 64 + k0));
            float4 kn4 = *((const float4*)(kn + (size_t)b * 64 + k0));
            x4.x = c * (bf16u_to_f(st4.x) - bf16u_to_f(df4.x)) * kn4.x;
            x4.y = c * (bf16u_to_f(st4.y) - bf16u_to_f(df4.y)) * kn4.y;
            x4.z = c * (bf16u_to_f(st4.z) - bf16u_to_f(df4.z)) * kn4.z;
            x4.w = c * (bf16u_to_f(st4.w) - bf16u_to_f(df4.w)) * kn4.w;
        }
        ushort4 xb;
        xb.x = f_to_bf16u(x4.x); xb.y = f_to_bf16u(x4.y);
        xb.z = f_to_bf16u(x4.z); xb.w = f_to_bf16u(x4.w);
        *((ushort4*)&xs_bf[r][k0]) = xb;
    }
    __syncthreads();

    const int w  = tid >> 6;
    const int l  = tid & 63;
    const int lr = l & 15;        // A row / B col / C col
    const int lg = l >> 4;        // k-group (8 contig k each)

    // ---- GEMM1: H1 = sigmoid(X[64x64] @ W1r[64x256] + b1)
    {
        short8v a0 = *(const short8v*)&xs_bf[16 * w + lr][lg * 8];
        short8v a1 = *(const short8v*)&xs_bf[16 * w + lr][32 + lg * 8];
        const unsigned short* w1base = W1t + (size_t)lr * 64 + lg * 8;
        #pragma unroll 4
        for (int n = 0; n < 16; ++n) {
            short8v bb0 = *(const short8v*)(w1base + n * 1024);
            short8v bb1 = *(const short8v*)(w1base + n * 1024 + 32);
            f32x4 acc = {0.f, 0.f, 0.f, 0.f};
            acc = __builtin_amdgcn_mfma_f32_16x16x32_bf16(a0, bb0, acc, 0, 0, 0);
            acc = __builtin_amdgcn_mfma_f32_16x16x32_bf16(a1, bb1, acc, 0, 0, 0);
            int col = n * 16 + lr;
            float bias = b1s[col];
            #pragma unroll
            for (int q = 0; q < 4; ++q)
                h1s[16 * w + lg * 4 + q][col] = f_to_bf16u(sigmoidf_(acc[q] + bias));
        }
    }
    __syncthreads();

    // ---- GEMM2: H2 = sigmoid(H1[64x256] @ W2r[256x128] + b2)
    {
        short8v ak[8];
        #pragma unroll
        for (int kk = 0; kk < 8; ++kk)
            ak[kk] = *(const short8v*)&h1s[16 * w + lr][kk * 32 + lg * 8];
        const unsigned short* w2base = W2t + (size_t)lr * 256 + lg * 8;
        #pragma unroll 2
        for (int n = 0; n < 8; ++n) {
            const unsigned short* bp = w2base + (size_t)n * 16 * 256;
            f32x4 acc = {0.f, 0.f, 0.f, 0.f};
            #pragma unroll
            for (int kk = 0; kk < 8; ++kk) {
                short8v bb = *(const short8v*)(bp + kk * 32);
                acc = __builtin_amdgcn_mfma_f32_16x16x32_bf16(ak[kk], bb, acc, 0, 0, 0);
            }
            int col = n * 16 + lr;
            float bias = b2s[col];
            #pragma unroll
            for (int q = 0; q < 4; ++q)
                h2s[16 * w + lg * 4 + q][col] = f_to_bf16u(sigmoidf_(acc[q] + bias));
        }
    }
    __syncthreads();

    // ---- GEMM3: out = sigmoid(H2 @ w3r + b3)   (64 rows, VALU)
    if (tid < 64) {
        int b = b0 + tid;
        if (b < B) {
            float acc = b3[0];
            const unsigned* h2r = (const unsigned*)&h2s[tid][0];
            #pragma unroll 8
            for (int jj = 0; jj < 64; ++jj) {
                unsigned hv = h2r[jj];
                acc += bf16lo(hv) * w3s[jj * 2 + 0] + bf16hi(hv) * w3s[jj * 2 + 1];
            }
            out[b] = sigmoidf_(acc);
        }
    }
}

extern "C" void kernel_launch(void* const* d_in, const int* in_sizes, int n_in,
                              void* d_out, int out_size, void* d_ws, size_t ws_size,
                              hipStream_t stream) {
    const float* stuW  = (const float*)d_in[0];
    const float* exerW = (const float*)d_in[1];
    const float* knowW = (const float*)d_in[2];
    const float* discW = (const float*)d_in[3];
    const float* W1 = (const float*)d_in[4];
    const float* b1 = (const float*)d_in[5];
    const float* W2 = (const float*)d_in[6];
    const float* b2 = (const float*)d_in[7];
    const float* W3 = (const float*)d_in[8];
    const float* b3 = (const float*)d_in[9];
    const int*   ui1_idx = (const int*)d_in[10];
    const float* ui1_val = (const float*)d_in[11];
    const int*   ui0_idx = (const int*)d_in[12];
    const float* ui0_val = (const float*)d_in[13];
    const int*   iu1_idx = (const int*)d_in[14];
    const float* iu1_val = (const float*)d_in[15];
    const int*   iu0_idx = (const int*)d_in[16];
    const float* iu0_val = (const float*)d_in[17];
    const float* kn      = (const float*)d_in[18];
    const int*   stu_id  = (const int*)d_in[19];
    const int*   exer_id = (const int*)d_in[20];
    float* out = (float*)d_out;

    const int S = in_sizes[0] / KDIM;
    const int E = in_sizes[1] / KDIM;
    const int B = in_sizes[19];
    const int n1 = in_sizes[11], n0 = in_sizes[13];
    const int m1 = in_sizes[15], m0 = in_sizes[17];
    const int ntot = n1 + n0 + m1 + m0;
    const int n_rows = S + E;
    const int NB = (n_rows + 255) / 256;            // 274
    const int nchunks = (ntot + CHUNK - 1) / CHUNK;

    char* p = (char*)d_ws;
    unsigned short* tab0 = (unsigned short*)p; p += (size_t)n_rows * KDIM * 2;   // 8.96 MB
    unsigned* edges      = (unsigned*)p;       p += (size_t)ntot * 4;            // 16 MB (final)
    unsigned* recPacked  = (unsigned*)p;                                         // 16 MB (temp)
    unsigned short* tabF = (unsigned short*)recPacked;   // aliases recPacked: dead before tabF written
    p += (size_t)ntot * 4;
    unsigned char* recRow = (unsigned char*)p; p += (size_t)ntot;                // 4 MB (temp)
    int* ptr    = (int*)p;                     p += (size_t)(n_rows + 1) * 4;
    int* bktCnt = (int*)p;                     p += (size_t)NBPAD * 4;
    int* bktBase= (int*)p;                     p += (size_t)(NBPAD + 1) * 4;
    int* gcurA  = (int*)p;                     p += (size_t)NBPAD * 4;
    p = (char*)(((uintptr_t)p + 255) & ~(uintptr_t)255);     // 16B+ align for vec loads
    unsigned short* W1t = (unsigned short*)p;  p += 256 * 64 * 2;                // 32 KB
    unsigned short* W2t = (unsigned short*)p;  p += 128 * 256 * 2;               // 64 KB
    float* w3r          = (float*)p;           p += 128 * 4;

    hipMemsetAsync(bktCnt, 0, (size_t)NB * 4, stream);

    prep_w<<<193, 256, 0, stream>>>(W1, W2, W3, W1t, W2t, w3r);

    embed_sig<<<(n_rows + 3) / 4, 256, 0, stream>>>(stuW, exerW, knowW, tab0, S, n_rows);

    bucket_count<<<nchunks, 256, 0, stream>>>(ui1_idx, ui0_idx, iu1_idx, iu0_idx,
                                              n1, n0, m1, S, bktCnt, ntot, NB);

    scan_tiny<<<1, 256, 0, stream>>>(bktCnt, bktBase, gcurA, NB);

    bin_scatter<<<nchunks, 256, 0, stream>>>(
        ui1_idx, ui1_val, ui0_idx, ui0_val, iu1_idx, iu1_val, iu0_idx, iu0_val,
        n1, n0, m1, m0, S, gcurA, recPacked, recRow, ntot, NB);

    row_sort<<<dim3(NB, 2), 256, 0, stream>>>(recPacked, recRow, bktBase,
                                              ptr, edges, n_rows, NB);

    pull_spmm<<<(n_rows + 3) / 4, 256, 0, stream>>>(tab0, ptr, edges, tabF, S, n_rows);

    tail_mlp<<<(B + 63) / 64, 256, 0, stream>>>(tabF, discW,
                                                W1t, b1, W2t, b2, w3r, b3,
                                                kn, stu_id, exer_id, out, S, B);
}

// Round 8
// 283.535 us; speedup vs baseline: 11.0971x; 1.0593x over previous
//
#include <hip/hip_runtime.h>

#define KDIM 64
#define NBPAD 512          // padded bucket-array size (NB = 274 here)
#define CHUNK 4096         // records per bin_scatter block

typedef __attribute__((ext_vector_type(8))) short short8v;   // 8 bf16 (4 VGPRs)
typedef __attribute__((ext_vector_type(4))) float f32x4;     // MFMA acc

__device__ __forceinline__ float bf16u_to_f(unsigned short u) {
    return __uint_as_float(((unsigned)u) << 16);
}
__device__ __forceinline__ float bf16lo(unsigned u) {
    return __uint_as_float(u << 16);
}
__device__ __forceinline__ float bf16hi(unsigned u) {
    return __uint_as_float(u & 0xFFFF0000u);
}
__device__ __forceinline__ unsigned short f_to_bf16u(float f) {
    unsigned b = __float_as_uint(f);
    b += 0x7FFF + ((b >> 16) & 1);          // round-to-nearest-even
    return (unsigned short)(b >> 16);
}
__device__ __forceinline__ unsigned pack2bf16(float lo, float hi) {
    return ((unsigned)f_to_bf16u(lo)) | (((unsigned)f_to_bf16u(hi)) << 16);
}
__device__ __forceinline__ float sigmoidf_(float x) {
    return 1.f / (1.f + __expf(-x));
}

// Unified row space over the 4 concatenated edge lists:
// [0,S) students (ui1,ui0), [S,S+E) exercises (iu1,iu0).
__device__ __forceinline__ int dec_row(int e,
    const int* __restrict__ i1, const int* __restrict__ i0,
    const int* __restrict__ j1, const int* __restrict__ j0,
    int n1, int n0, int m1, int S_)
{
    if (e < n1) return i1[e];
    e -= n1;
    if (e < n0) return i0[e];
    e -= n0;
    if (e < m1) return S_ + j1[e];
    e -= m1;
    return S_ + j0[e];
}

__device__ __forceinline__ void dec_full(int e,
    const int* __restrict__ i1, const float* __restrict__ v1,
    const int* __restrict__ i0, const float* __restrict__ v0,
    const int* __restrict__ j1, const float* __restrict__ w1,
    const int* __restrict__ j0, const float* __restrict__ w0,
    int n1, int n0, int m1, int m0, int S_,
    unsigned& row, unsigned& pk)
{
    int col; float v;
    if (e < n1) { row = (unsigned)i1[e]; col = i1[n1 + e]; v = v1[e]; }
    else if (e < n1 + n0) { int le = e - n1; row = (unsigned)i0[le]; col = i0[n0 + le]; v = v0[le]; }
    else if (e < n1 + n0 + m1) { int le = e - n1 - n0; row = (unsigned)(S_ + j1[le]); col = j1[m1 + le]; v = w1[le]; }
    else { int le = e - n1 - n0 - m1; row = (unsigned)(S_ + j0[le]); col = j0[m0 + le]; v = w0[le]; }
    pk = ((unsigned)col << 16) | (unsigned)f_to_bf16u(v);
}

// -------- Phase 1: tab0[row] = sigmoid(emb_row @ know_W^T)  (unified bf16 table)
__global__ __launch_bounds__(256) void embed_sig(
    const float* __restrict__ stuW, const float* __restrict__ exerW,
    const float* __restrict__ knowW,
    unsigned short* __restrict__ tab0, int S, int n_rows)
{
    __shared__ float kwT[64][65];
    for (int i = threadIdx.x; i < 64 * 64; i += 256) {
        int k = i >> 6, d = i & 63;
        kwT[d][k] = knowW[i];
    }
    __syncthreads();

    const int lane = threadIdx.x & 63;
    const int row = blockIdx.x * 4 + (threadIdx.x >> 6);
    if (row >= n_rows) return;
    const float* a = (row < S) ? (stuW + (size_t)row * KDIM)
                               : (exerW + (size_t)(row - S) * KDIM);
    const float4* a4 = (const float4*)a;
    float acc = 0.f;
    #pragma unroll
    for (int d4 = 0; d4 < 16; ++d4) {
        float4 av = a4[d4];
        acc += av.x * kwT[d4 * 4 + 0][lane];
        acc += av.y * kwT[d4 * 4 + 1][lane];
        acc += av.z * kwT[d4 * 4 + 2][lane];
        acc += av.w * kwT[d4 * 4 + 3][lane];
    }
    tab0[(size_t)row * KDIM + lane] = f_to_bf16u(sigmoidf_(acc));
}

// -------- weight prep: relu + transpose + bf16 (W1t[256n][64k], W2t[128n][256k], w3r)
__global__ __launch_bounds__(256) void prep_w(
    const float* __restrict__ W1, const float* __restrict__ W2,
    const float* __restrict__ W3,
    unsigned short* __restrict__ W1t, unsigned short* __restrict__ W2t,
    float* __restrict__ w3r)
{
    int i = blockIdx.x * 256 + threadIdx.x;
    if (i < 256 * 64) {                     // W1t[n][k] = relu(W1[k][n])
        int n = i >> 6, k = i & 63;
        W1t[i] = f_to_bf16u(fmaxf(W1[k * 256 + n], 0.f));
        return;
    }
    int j = i - 256 * 64;
    if (j < 128 * 256) {                    // W2t[n][k] = relu(W2[k][n])
        int n = j >> 8, k = j & 255;
        W2t[j] = f_to_bf16u(fmaxf(W2[k * 128 + n], 0.f));
        return;
    }
    int l = j - 128 * 256;
    if (l < 128) w3r[l] = fmaxf(W3[l], 0.f);
}

// -------- bucket histogram: LDS-aggregated, few global atomics (274 counters)
__global__ __launch_bounds__(256) void bucket_count(
    const int* __restrict__ i1, const int* __restrict__ i0,
    const int* __restrict__ j1, const int* __restrict__ j0,
    int n1, int n0, int m1, int S_,
    int* __restrict__ bktCnt, int ntot, int NB)
{
    __shared__ int h[NBPAD];
    for (int i = threadIdx.x; i < NBPAD; i += 256) h[i] = 0;
    __syncthreads();
    const int e0 = blockIdx.x * CHUNK;
    #pragma unroll
    for (int it = 0; it < 16; ++it) {
        int e = e0 + it * 256 + threadIdx.x;
        if (e < ntot) atomicAdd(&h[dec_row(e, i1, i0, j1, j0, n1, n0, m1, S_) >> 8], 1);
    }
    __syncthreads();
    for (int b = threadIdx.x; b < NB; b += 256)
        if (h[b]) atomicAdd(&bktCnt[b], h[b]);
}

// -------- exclusive scan of NB bucket counts -> bktBase (+ cursor copy gcurA)
__global__ __launch_bounds__(256) void scan_tiny(
    const int* __restrict__ bktCnt, int* __restrict__ bktBase,
    int* __restrict__ gcurA, int NB)
{
    __shared__ int s[NBPAD + 1];
    for (int i = threadIdx.x; i < NB; i += 256) s[i] = bktCnt[i];
    __syncthreads();
    if (threadIdx.x == 0) {
        int acc = 0;
        for (int b = 0; b < NB; ++b) { int c = s[b]; s[b] = acc; acc += c; }
        s[NB] = acc;
    }
    __syncthreads();
    for (int i = threadIdx.x; i <= NB; i += 256) bktBase[i] = s[i];
    for (int i = threadIdx.x; i < NB; i += 256) gcurA[i] = s[i];
}

// -------- binned scatter: LDS reorder by 256-row bucket, drain coalesced runs.
__global__ __launch_bounds__(256) void bin_scatter(
    const int* __restrict__ i1, const float* __restrict__ v1,
    const int* __restrict__ i0, const float* __restrict__ v0,
    const int* __restrict__ j1, const float* __restrict__ w1,
    const int* __restrict__ j0, const float* __restrict__ w0,
    int n1, int n0, int m1, int m0, int S_,
    int* __restrict__ gcurA,
    unsigned* __restrict__ recPacked, unsigned char* __restrict__ recRow,
    int ntot, int NB)
{
    __shared__ int h[NBPAD], sstart[NBPAD], lbase[NBPAD], gdst[NBPAD];
    __shared__ unsigned stageP[CHUNK];
    __shared__ unsigned char stageR[CHUNK];
    __shared__ unsigned short stageB[CHUNK];
    const int tid = threadIdx.x;
    const int e0 = blockIdx.x * CHUNK;

    for (int i = tid; i < NBPAD; i += 256) h[i] = 0;
    __syncthreads();

    unsigned rrow[16], rpk[16];
    #pragma unroll
    for (int it = 0; it < 16; ++it) {
        int e = e0 + it * 256 + tid;
        if (e < ntot) {
            dec_full(e, i1, v1, i0, v0, j1, w1, j0, w0, n1, n0, m1, m0, S_,
                     rrow[it], rpk[it]);
            atomicAdd(&h[rrow[it] >> 8], 1);
        } else {
            rrow[it] = 0xFFFFFFFFu;
        }
    }
    __syncthreads();

    {   // exclusive prefix over NB buckets; thread t owns buckets t and t+256
        int acc0 = 0, acc1 = 0;
        for (int b = 0; b < NB; ++b) {
            int hv = h[b];
            if (b < tid)       acc0 += hv;
            if (b < tid + 256) acc1 += hv;
        }
        sstart[tid] = acc0; lbase[tid] = acc0;
        int c0 = h[tid];
        if (c0 > 0) gdst[tid] = atomicAdd(&gcurA[tid], c0);
        if (tid + 256 < NB) {
            sstart[tid + 256] = acc1; lbase[tid + 256] = acc1;
            int c1 = h[tid + 256];
            if (c1 > 0) gdst[tid + 256] = atomicAdd(&gcurA[tid + 256], c1);
        }
    }
    __syncthreads();

    #pragma unroll
    for (int it = 0; it < 16; ++it) {
        if (rrow[it] != 0xFFFFFFFFu) {
            int bkt = rrow[it] >> 8;
            int slot = atomicAdd(&lbase[bkt], 1);
            stageP[slot] = rpk[it];
            stageR[slot] = (unsigned char)(rrow[it] & 255u);
            stageB[slot] = (unsigned short)bkt;
        }
    }
    __syncthreads();

    int cnt = ntot - e0; if (cnt > CHUNK) cnt = CHUNK;
    for (int i = tid; i < cnt; i += 256) {
        int bkt = stageB[i];
        int dst = gdst[bkt] + (i - sstart[bkt]);
        recPacked[dst] = stageP[i];
        recRow[dst]   = stageR[i];
    }
}

// -------- per-bucket row sort WITH built-in per-row histogram + scan + ptr emit.
__global__ __launch_bounds__(256) void row_sort(
    const unsigned* __restrict__ recPacked, const unsigned char* __restrict__ recRow,
    const int* __restrict__ bktBase,
    int* __restrict__ ptr, unsigned* __restrict__ edges, int n_rows, int NB)
{
    __shared__ int h0[256], h1[256], sc[256], cur[256];
    const int b = blockIdx.x;
    const int half = blockIdx.y;
    const int tid = threadIdx.x;
    const int r0 = b << 8;
    const int start = bktBase[b], end = bktBase[b + 1];
    const int mid = start + ((end - start) >> 1);

    h0[tid] = 0; h1[tid] = 0;
    __syncthreads();

    for (int i = start + tid; i < end; i += 256) {
        int r = (int)recRow[i];
        if (i < mid) atomicAdd(&h0[r], 1);
        else         atomicAdd(&h1[r], 1);
    }
    __syncthreads();

    const int tot = h0[tid] + h1[tid];
    sc[tid] = tot;
    __syncthreads();
    for (int o = 1; o < 256; o <<= 1) {
        int add = (tid >= o) ? sc[tid - o] : 0;
        __syncthreads();
        sc[tid] += add;
        __syncthreads();
    }
    const int excl = sc[tid] - tot;

    if (half == 0) {
        int grow = r0 + tid;
        if (grow < n_rows) ptr[grow] = start + excl;
        if (b == NB - 1 && tid == 0) ptr[n_rows] = end;
    }
    cur[tid] = excl + (half ? h0[tid] : 0);
    __syncthreads();

    const int s0 = half ? mid : start;
    const int s1 = half ? end : mid;
    for (int i = s0 + tid; i < s1; i += 256) {
        unsigned pk = recPacked[i];
        int r = (int)recRow[i];
        int dst = start + atomicAdd(&cur[r], 1);
        edges[dst] = pk;
    }
}

// -------- Pull SpMM v2: one wave per output row; 8 edges per iteration.
// Lane split: g = lane>>3 selects edge in octet, s = lane&7 covers k = 8s..8s+7
// via one uint4 (16 B = 8 bf16) gather. Batch prefetch of next 64 records.
__global__ __launch_bounds__(256) void pull_spmm(
    const unsigned short* __restrict__ tab0,
    const int* __restrict__ ptr, const unsigned* __restrict__ edges,
    unsigned short* __restrict__ tabF, int S_, int n_rows)
{
    const int w = blockIdx.x * 4 + (threadIdx.x >> 6);
    if (w >= n_rows) return;
    const int lane = threadIdx.x & 63;
    const int g = lane >> 3;      // 8 edge-groups
    const int s = lane & 7;       // k-range 8s..8s+7

    // student rows gather exercise half (offset S), exercise rows gather student half
    const unsigned short* Xs = tab0 + ((w < S_) ? ((size_t)S_ << 6) : (size_t)0)
                                    + (size_t)s * 8;

    float acc[8];
    #pragma unroll
    for (int i = 0; i < 8; ++i) acc[i] = 0.f;

    int e = ptr[w];
    const int ee = ptr[w + 1];
    unsigned u = (e + lane < ee) ? edges[e + lane] : 0u;
    while (e < ee) {
        int m = ee - e; if (m > 64) m = 64;
        unsigned un = (e + 64 + lane < ee) ? edges[e + 64 + lane] : 0u;  // prefetch
        int iters = (m + 7) >> 3;
        #pragma unroll 4
        for (int jj = 0; jj < iters; ++jj) {
            unsigned uj = __shfl(u, jj * 8 + g);     // 0-word: col 0, val 0 -> harmless
            float v = __uint_as_float(uj << 16);     // low 16 = bf16 val
            uint4 xv = *(const uint4*)(Xs + (((size_t)(uj >> 16)) << 6));
            acc[0] = fmaf(v, bf16lo(xv.x), acc[0]);
            acc[1] = fmaf(v, bf16hi(xv.x), acc[1]);
            acc[2] = fmaf(v, bf16lo(xv.y), acc[2]);
            acc[3] = fmaf(v, bf16hi(xv.y), acc[3]);
            acc[4] = fmaf(v, bf16lo(xv.z), acc[4]);
            acc[5] = fmaf(v, bf16hi(xv.z), acc[5]);
            acc[6] = fmaf(v, bf16lo(xv.w), acc[6]);
            acc[7] = fmaf(v, bf16hi(xv.w), acc[7]);
        }
        u = un;
        e += m;
    }

    // combine the 8 edge-groups (lane bits 3,4,5)
    #pragma unroll
    for (int i = 0; i < 8; ++i) {
        acc[i] += __shfl_xor(acc[i], 8);
        acc[i] += __shfl_xor(acc[i], 16);
        acc[i] += __shfl_xor(acc[i], 32);
    }

    if (g == 0) {
        const uint4 x0 = *(const uint4*)(tab0 + ((size_t)w << 6) + (size_t)s * 8);
        uint4 o;
        o.x = pack2bf16(acc[0] + bf16lo(x0.x), acc[1] + bf16hi(x0.x));
        o.y = pack2bf16(acc[2] + bf16lo(x0.y), acc[3] + bf16hi(x0.y));
        o.z = pack2bf16(acc[4] + bf16lo(x0.z), acc[5] + bf16hi(x0.z));
        o.w = pack2bf16(acc[6] + bf16lo(x0.w), acc[7] + bf16hi(x0.w));
        *(uint4*)(tabF + ((size_t)w << 6) + (size_t)s * 8) = o;
    }
}

// -------- MFMA tail: gather -> GEMM1(64x256x64) -> GEMM2(64x128x256) -> dot.
// One block = 64 batch rows, 4 waves; wave w owns rows 16w..16w+15.
// Fragment layouts (gfx950 16x16x32 bf16): A: row=l&15, k=(l>>4)*8+j (8 contig);
// B: col=l&15, k=(l>>4)*8+j (8 contig in W^T layout); C: col=l&15, row=(l>>4)*4+q.
__global__ __launch_bounds__(256) void tail_mlp(
    const unsigned short* __restrict__ tabF,
    const float* __restrict__ discW,
    const unsigned short* __restrict__ W1t, const float* __restrict__ b1,
    const unsigned short* __restrict__ W2t, const float* __restrict__ b2,
    const float* __restrict__ w3r, const float* __restrict__ b3,
    const float* __restrict__ kn, const int* __restrict__ stu_id,
    const int* __restrict__ exer_id, float* __restrict__ out, int S_, int B)
{
    __shared__ __align__(16) unsigned short xs_bf[64][72];   // 9.0 KB (pad: 2-way banks)
    __shared__ __align__(16) unsigned short h1s[64][264];    // 33.0 KB
    __shared__ __align__(16) unsigned short h2s[64][136];    // 17.0 KB
    __shared__ float b1s[256], b2s[128], w3s[128];
    const int tid = threadIdx.x;
    const int b0 = blockIdx.x * 64;

    b1s[tid] = b1[tid];
    if (tid < 128) { b2s[tid] = b2[tid]; w3s[tid] = w3r[tid]; }

    // ---- phase 0: x = disc*(stat-diff)/3*kn -> bf16 LDS tile (vectorized x4)
    #pragma unroll
    for (int i = 0; i < 4; ++i) {
        int e4 = (i * 256 + tid) * 4;
        int r = e4 >> 6, k0 = e4 & 63;
        int b = b0 + r;
        float4 x4 = make_float4(0.f, 0.f, 0.f, 0.f);
        if (b < B) {
            int sid = stu_id[b], eid = exer_id[b];
            float c = sigmoidf_(discW[eid]) * (1.f / 3.f);
            ushort4 st4 = *((const ushort4*)(tabF + (size_t)sid * 64 + k0));
            ushort4 df4 = *((const ushort4*)(tabF + ((size_t)(S_ + eid)) * 64 + k0));
            float4 kn4 = *((const float4*)(kn + (size_t)b * 64 + k0));
            x4.x = c * (bf16u_to_f(st4.x) - bf16u_to_f(df4.x)) * kn4.x;
            x4.y = c * (bf16u_to_f(st4.y) - bf16u_to_f(df4.y)) * kn4.y;
            x4.z = c * (bf16u_to_f(st4.z) - bf16u_to_f(df4.z)) * kn4.z;
            x4.w = c * (bf16u_to_f(st4.w) - bf16u_to_f(df4.w)) * kn4.w;
        }
        ushort4 xb;
        xb.x = f_to_bf16u(x4.x); xb.y = f_to_bf16u(x4.y);
        xb.z = f_to_bf16u(x4.z); xb.w = f_to_bf16u(x4.w);
        *((ushort4*)&xs_bf[r][k0]) = xb;
    }
    __syncthreads();

    const int w  = tid >> 6;
    const int l  = tid & 63;
    const int lr = l & 15;        // A row / B col / C col
    const int lg = l >> 4;        // k-group (8 contig k each)

    // ---- GEMM1: H1 = sigmoid(X[64x64] @ W1r[64x256] + b1)
    {
        short8v a0 = *(const short8v*)&xs_bf[16 * w + lr][lg * 8];
        short8v a1 = *(const short8v*)&xs_bf[16 * w + lr][32 + lg * 8];
        const unsigned short* w1base = W1t + (size_t)lr * 64 + lg * 8;
        #pragma unroll 4
        for (int n = 0; n < 16; ++n) {
            short8v bb0 = *(const short8v*)(w1base + n * 1024);
            short8v bb1 = *(const short8v*)(w1base + n * 1024 + 32);
            f32x4 acc = {0.f, 0.f, 0.f, 0.f};
            acc = __builtin_amdgcn_mfma_f32_16x16x32_bf16(a0, bb0, acc, 0, 0, 0);
            acc = __builtin_amdgcn_mfma_f32_16x16x32_bf16(a1, bb1, acc, 0, 0, 0);
            int col = n * 16 + lr;
            float bias = b1s[col];
            #pragma unroll
            for (int q = 0; q < 4; ++q)
                h1s[16 * w + lg * 4 + q][col] = f_to_bf16u(sigmoidf_(acc[q] + bias));
        }
    }
    __syncthreads();

    // ---- GEMM2: H2 = sigmoid(H1[64x256] @ W2r[256x128] + b2)
    {
        short8v ak[8];
        #pragma unroll
        for (int kk = 0; kk < 8; ++kk)
            ak[kk] = *(const short8v*)&h1s[16 * w + lr][kk * 32 + lg * 8];
        const unsigned short* w2base = W2t + (size_t)lr * 256 + lg * 8;
        #pragma unroll 2
        for (int n = 0; n < 8; ++n) {
            const unsigned short* bp = w2base + (size_t)n * 16 * 256;
            f32x4 acc = {0.f, 0.f, 0.f, 0.f};
            #pragma unroll
            for (int kk = 0; kk < 8; ++kk) {
                short8v bb = *(const short8v*)(bp + kk * 32);
                acc = __builtin_amdgcn_mfma_f32_16x16x32_bf16(ak[kk], bb, acc, 0, 0, 0);
            }
            int col = n * 16 + lr;
            float bias = b2s[col];
            #pragma unroll
            for (int q = 0; q < 4; ++q)
                h2s[16 * w + lg * 4 + q][col] = f_to_bf16u(sigmoidf_(acc[q] + bias));
        }
    }
    __syncthreads();

    // ---- GEMM3: out = sigmoid(H2 @ w3r + b3)   (64 rows, VALU)
    if (tid < 64) {
        int b = b0 + tid;
        if (b < B) {
            float acc = b3[0];
            const unsigned* h2r = (const unsigned*)&h2s[tid][0];
            #pragma unroll 8
            for (int jj = 0; jj < 64; ++jj) {
                unsigned hv = h2r[jj];
                acc += bf16lo(hv) * w3s[jj * 2 + 0] + bf16hi(hv) * w3s[jj * 2 + 1];
            }
            out[b] = sigmoidf_(acc);
        }
    }
}

extern "C" void kernel_launch(void* const* d_in, const int* in_sizes, int n_in,
                              void* d_out, int out_size, void* d_ws, size_t ws_size,
                              hipStream_t stream) {
    const float* stuW  = (const float*)d_in[0];
    const float* exerW = (const float*)d_in[1];
    const float* knowW = (const float*)d_in[2];
    const float* discW = (const float*)d_in[3];
    const float* W1 = (const float*)d_in[4];
    const float* b1 = (const float*)d_in[5];
    const float* W2 = (const float*)d_in[6];
    const float* b2 = (const float*)d_in[7];
    const float* W3 = (const float*)d_in[8];
    const float* b3 = (const float*)d_in[9];
    const int*   ui1_idx = (const int*)d_in[10];
    const float* ui1_val = (const float*)d_in[11];
    const int*   ui0_idx = (const int*)d_in[12];
    const float* ui0_val = (const float*)d_in[13];
    const int*   iu1_idx = (const int*)d_in[14];
    const float* iu1_val = (const float*)d_in[15];
    const int*   iu0_idx = (const int*)d_in[16];
    const float* iu0_val = (const float*)d_in[17];
    const float* kn      = (const float*)d_in[18];
    const int*   stu_id  = (const int*)d_in[19];
    const int*   exer_id = (const int*)d_in[20];
    float* out = (float*)d_out;

    const int S = in_sizes[0] / KDIM;
    const int E = in_sizes[1] / KDIM;
    const int B = in_sizes[19];
    const int n1 = in_sizes[11], n0 = in_sizes[13];
    const int m1 = in_sizes[15], m0 = in_sizes[17];
    const int ntot = n1 + n0 + m1 + m0;
    const int n_rows = S + E;
    const int NB = (n_rows + 255) / 256;            // 274
    const int nchunks = (ntot + CHUNK - 1) / CHUNK;

    char* p = (char*)d_ws;
    unsigned short* tab0 = (unsigned short*)p; p += (size_t)n_rows * KDIM * 2;   // 8.96 MB
    unsigned* edges      = (unsigned*)p;       p += (size_t)ntot * 4;            // 16 MB (final)
    unsigned* recPacked  = (unsigned*)p;                                         // 16 MB (temp)
    unsigned short* tabF = (unsigned short*)recPacked;   // aliases recPacked: dead before tabF written
    p += (size_t)ntot * 4;
    unsigned char* recRow = (unsigned char*)p; p += (size_t)ntot;                // 4 MB (temp)
    int* ptr    = (int*)p;                     p += (size_t)(n_rows + 1) * 4;
    int* bktCnt = (int*)p;                     p += (size_t)NBPAD * 4;
    int* bktBase= (int*)p;                     p += (size_t)(NBPAD + 1) * 4;
    int* gcurA  = (int*)p;                     p += (size_t)NBPAD * 4;
    p = (char*)(((uintptr_t)p + 255) & ~(uintptr_t)255);     // 16B+ align for vec loads
    unsigned short* W1t = (unsigned short*)p;  p += 256 * 64 * 2;                // 32 KB
    unsigned short* W2t = (unsigned short*)p;  p += 128 * 256 * 2;               // 64 KB
    float* w3r          = (float*)p;           p += 128 * 4;

    hipMemsetAsync(bktCnt, 0, (size_t)NB * 4, stream);

    prep_w<<<193, 256, 0, stream>>>(W1, W2, W3, W1t, W2t, w3r);

    embed_sig<<<(n_rows + 3) / 4, 256, 0, stream>>>(stuW, exerW, knowW, tab0, S, n_rows);

    bucket_count<<<nchunks, 256, 0, stream>>>(ui1_idx, ui0_idx, iu1_idx, iu0_idx,
                                              n1, n0, m1, S, bktCnt, ntot, NB);

    scan_tiny<<<1, 256, 0, stream>>>(bktCnt, bktBase, gcurA, NB);

    bin_scatter<<<nchunks, 256, 0, stream>>>(
        ui1_idx, ui1_val, ui0_idx, ui0_val, iu1_idx, iu1_val, iu0_idx, iu0_val,
        n1, n0, m1, m0, S, gcurA, recPacked, recRow, ntot, NB);

    row_sort<<<dim3(NB, 2), 256, 0, stream>>>(recPacked, recRow, bktBase,
                                              ptr, edges, n_rows, NB);

    pull_spmm<<<(n_rows + 3) / 4, 256, 0, stream>>>(tab0, ptr, edges, tabF, S, n_rows);

    tail_mlp<<<(B + 63) / 64, 256, 0, stream>>>(tabF, discW,
                                                W1t, b1, W2t, b2, w3r, b3,
                                                kn, stu_id, exer_id, out, S, B);
}

// Round 9
// 242.039 us; speedup vs baseline: 12.9996x; 1.1714x over previous
//
#include <hip/hip_runtime.h>

#define KDIM 64
#define NBPAD 512          // padded bucket-array size (NB = 274 here)
#define CHUNK 4096         // records per bin_scatter block

typedef __attribute__((ext_vector_type(8))) short short8v;   // 8 bf16 (4 VGPRs)
typedef __attribute__((ext_vector_type(4))) float f32x4;     // MFMA acc

__device__ __forceinline__ float bf16u_to_f(unsigned short u) {
    return __uint_as_float(((unsigned)u) << 16);
}
__device__ __forceinline__ float bf16lo(unsigned u) {
    return __uint_as_float(u << 16);
}
__device__ __forceinline__ float bf16hi(unsigned u) {
    return __uint_as_float(u & 0xFFFF0000u);
}
__device__ __forceinline__ unsigned short f_to_bf16u(float f) {
    unsigned b = __float_as_uint(f);
    b += 0x7FFF + ((b >> 16) & 1);          // round-to-nearest-even
    return (unsigned short)(b >> 16);
}
__device__ __forceinline__ unsigned pack2bf16(float lo, float hi) {
    return ((unsigned)f_to_bf16u(lo)) | (((unsigned)f_to_bf16u(hi)) << 16);
}
__device__ __forceinline__ float sigmoidf_(float x) {
    return 1.f / (1.f + __expf(-x));
}

// Unified row space over the 4 concatenated edge lists:
// [0,S) students (ui1,ui0), [S,S+E) exercises (iu1,iu0).
__device__ __forceinline__ int dec_row(int e,
    const int* __restrict__ i1, const int* __restrict__ i0,
    const int* __restrict__ j1, const int* __restrict__ j0,
    int n1, int n0, int m1, int S_)
{
    if (e < n1) return i1[e];
    e -= n1;
    if (e < n0) return i0[e];
    e -= n0;
    if (e < m1) return S_ + j1[e];
    e -= m1;
    return S_ + j0[e];
}

__device__ __forceinline__ void dec_full(int e,
    const int* __restrict__ i1, const float* __restrict__ v1,
    const int* __restrict__ i0, const float* __restrict__ v0,
    const int* __restrict__ j1, const float* __restrict__ w1,
    const int* __restrict__ j0, const float* __restrict__ w0,
    int n1, int n0, int m1, int m0, int S_,
    unsigned& row, unsigned& pk)
{
    int col; float v;
    if (e < n1) { row = (unsigned)i1[e]; col = i1[n1 + e]; v = v1[e]; }
    else if (e < n1 + n0) { int le = e - n1; row = (unsigned)i0[le]; col = i0[n0 + le]; v = v0[le]; }
    else if (e < n1 + n0 + m1) { int le = e - n1 - n0; row = (unsigned)(S_ + j1[le]); col = j1[m1 + le]; v = w1[le]; }
    else { int le = e - n1 - n0 - m1; row = (unsigned)(S_ + j0[le]); col = j0[m0 + le]; v = w0[le]; }
    pk = ((unsigned)col << 16) | (unsigned)f_to_bf16u(v);
}

// -------- weight prep: relu + transpose + bf16 (W1t[256n][64k], W2t[128n][256k],
// w3r) + know_W bf16 copy (knb[64][64]).
__global__ __launch_bounds__(256) void prep_w(
    const float* __restrict__ W1, const float* __restrict__ W2,
    const float* __restrict__ W3, const float* __restrict__ knowW,
    unsigned short* __restrict__ W1t, unsigned short* __restrict__ W2t,
    float* __restrict__ w3r, unsigned short* __restrict__ knb)
{
    int i = blockIdx.x * 256 + threadIdx.x;
    if (i < 256 * 64) {                     // W1t[n][k] = relu(W1[k][n])
        int n = i >> 6, k = i & 63;
        W1t[i] = f_to_bf16u(fmaxf(W1[k * 256 + n], 0.f));
        return;
    }
    int j = i - 256 * 64;
    if (j < 128 * 256) {                    // W2t[n][k] = relu(W2[k][n])
        int n = j >> 8, k = j & 255;
        W2t[j] = f_to_bf16u(fmaxf(W2[k * 128 + n], 0.f));
        return;
    }
    int l = j - 128 * 256;
    if (l < 128) { w3r[l] = fmaxf(W3[l], 0.f); return; }
    int m = l - 128;
    if (m < 64 * 64) knb[m] = f_to_bf16u(knowW[m]);
}

// -------- Phase 1 (MFMA): tab0 = sigmoid(emb @ know_W^T), 64 rows/block.
// Fragment layouts as validated in tail_mlp: A row=l&15 k=(l>>4)*8+j;
// B col=l&15 k=(l>>4)*8+j (knb row-major [col][k]); C col=l&15 row=(l>>4)*4+q.
__global__ __launch_bounds__(256) void embed_mfma(
    const float* __restrict__ stuW, const float* __restrict__ exerW,
    const unsigned short* __restrict__ knb,
    unsigned short* __restrict__ tab0, int S, int n_rows)
{
    const int tid = threadIdx.x;
    const int w = tid >> 6, l = tid & 63;
    const int lr = l & 15, lg = l >> 4;
    const int r0 = blockIdx.x * 64 + 16 * w;

    const int arow = min(r0 + lr, n_rows - 1);
    const float* a = (arow < S) ? (stuW + (size_t)arow * KDIM)
                                : (exerW + (size_t)(arow - S) * KDIM);
    float4 v0 = *((const float4*)(a + lg * 8));
    float4 v1 = *((const float4*)(a + lg * 8 + 4));
    float4 v2 = *((const float4*)(a + 32 + lg * 8));
    float4 v3 = *((const float4*)(a + 32 + lg * 8 + 4));
    union { unsigned u[4]; short8v s; } A0, A1;
    A0.u[0] = pack2bf16(v0.x, v0.y); A0.u[1] = pack2bf16(v0.z, v0.w);
    A0.u[2] = pack2bf16(v1.x, v1.y); A0.u[3] = pack2bf16(v1.z, v1.w);
    A1.u[0] = pack2bf16(v2.x, v2.y); A1.u[1] = pack2bf16(v2.z, v2.w);
    A1.u[2] = pack2bf16(v3.x, v3.y); A1.u[3] = pack2bf16(v3.z, v3.w);

    #pragma unroll
    for (int n = 0; n < 4; ++n) {
        const unsigned short* bp = knb + ((size_t)(n * 16 + lr)) * KDIM + lg * 8;
        short8v b0 = *(const short8v*)bp;
        short8v b1 = *(const short8v*)(bp + 32);
        f32x4 acc = {0.f, 0.f, 0.f, 0.f};
        acc = __builtin_amdgcn_mfma_f32_16x16x32_bf16(A0.s, b0, acc, 0, 0, 0);
        acc = __builtin_amdgcn_mfma_f32_16x16x32_bf16(A1.s, b1, acc, 0, 0, 0);
        #pragma unroll
        for (int q = 0; q < 4; ++q) {
            int srow = r0 + lg * 4 + q;
            if (srow < n_rows)
                tab0[(size_t)srow * KDIM + n * 16 + lr] = f_to_bf16u(sigmoidf_(acc[q]));
        }
    }
}

// -------- bucket histogram: LDS-aggregated, few global atomics (274 counters)
__global__ __launch_bounds__(256) void bucket_count(
    const int* __restrict__ i1, const int* __restrict__ i0,
    const int* __restrict__ j1, const int* __restrict__ j0,
    int n1, int n0, int m1, int S_,
    int* __restrict__ bktCnt, int ntot, int NB)
{
    __shared__ int h[NBPAD];
    for (int i = threadIdx.x; i < NBPAD; i += 256) h[i] = 0;
    __syncthreads();
    const int e0 = blockIdx.x * CHUNK;
    #pragma unroll
    for (int it = 0; it < 16; ++it) {
        int e = e0 + it * 256 + threadIdx.x;
        if (e < ntot) atomicAdd(&h[dec_row(e, i1, i0, j1, j0, n1, n0, m1, S_) >> 8], 1);
    }
    __syncthreads();
    for (int b = threadIdx.x; b < NB; b += 256)
        if (h[b]) atomicAdd(&bktCnt[b], h[b]);
}

// -------- exclusive scan of NB bucket counts -> bktBase (+ cursor copy gcurA)
__global__ __launch_bounds__(256) void scan_tiny(
    const int* __restrict__ bktCnt, int* __restrict__ bktBase,
    int* __restrict__ gcurA, int NB)
{
    __shared__ int s[NBPAD + 1];
    for (int i = threadIdx.x; i < NB; i += 256) s[i] = bktCnt[i];
    __syncthreads();
    if (threadIdx.x == 0) {
        int acc = 0;
        for (int b = 0; b < NB; ++b) { int c = s[b]; s[b] = acc; acc += c; }
        s[NB] = acc;
    }
    __syncthreads();
    for (int i = threadIdx.x; i <= NB; i += 256) bktBase[i] = s[i];
    for (int i = threadIdx.x; i < NB; i += 256) gcurA[i] = s[i];
}

// -------- binned scatter: LDS reorder by 256-row bucket, drain coalesced runs.
__global__ __launch_bounds__(256) void bin_scatter(
    const int* __restrict__ i1, const float* __restrict__ v1,
    const int* __restrict__ i0, const float* __restrict__ v0,
    const int* __restrict__ j1, const float* __restrict__ w1,
    const int* __restrict__ j0, const float* __restrict__ w0,
    int n1, int n0, int m1, int m0, int S_,
    int* __restrict__ gcurA,
    unsigned* __restrict__ recPacked, unsigned char* __restrict__ recRow,
    int ntot, int NB)
{
    __shared__ int h[NBPAD], sstart[NBPAD], lbase[NBPAD], gdst[NBPAD];
    __shared__ unsigned stageP[CHUNK];
    __shared__ unsigned char stageR[CHUNK];
    __shared__ unsigned short stageB[CHUNK];
    const int tid = threadIdx.x;
    const int e0 = blockIdx.x * CHUNK;

    for (int i = tid; i < NBPAD; i += 256) h[i] = 0;
    __syncthreads();

    unsigned rrow[16], rpk[16];
    #pragma unroll
    for (int it = 0; it < 16; ++it) {
        int e = e0 + it * 256 + tid;
        if (e < ntot) {
            dec_full(e, i1, v1, i0, v0, j1, w1, j0, w0, n1, n0, m1, m0, S_,
                     rrow[it], rpk[it]);
            atomicAdd(&h[rrow[it] >> 8], 1);
        } else {
            rrow[it] = 0xFFFFFFFFu;
        }
    }
    __syncthreads();

    {   // exclusive prefix over NB buckets; thread t owns buckets t and t+256
        int acc0 = 0, acc1 = 0;
        for (int b = 0; b < NB; ++b) {
            int hv = h[b];
            if (b < tid)       acc0 += hv;
            if (b < tid + 256) acc1 += hv;
        }
        sstart[tid] = acc0; lbase[tid] = acc0;
        int c0 = h[tid];
        if (c0 > 0) gdst[tid] = atomicAdd(&gcurA[tid], c0);
        if (tid + 256 < NB) {
            sstart[tid + 256] = acc1; lbase[tid + 256] = acc1;
            int c1 = h[tid + 256];
            if (c1 > 0) gdst[tid + 256] = atomicAdd(&gcurA[tid + 256], c1);
        }
    }
    __syncthreads();

    #pragma unroll
    for (int it = 0; it < 16; ++it) {
        if (rrow[it] != 0xFFFFFFFFu) {
            int bkt = rrow[it] >> 8;
            int slot = atomicAdd(&lbase[bkt], 1);
            stageP[slot] = rpk[it];
            stageR[slot] = (unsigned char)(rrow[it] & 255u);
            stageB[slot] = (unsigned short)bkt;
        }
    }
    __syncthreads();

    int cnt = ntot - e0; if (cnt > CHUNK) cnt = CHUNK;
    for (int i = tid; i < cnt; i += 256) {
        int bkt = stageB[i];
        int dst = gdst[bkt] + (i - sstart[bkt]);
        recPacked[dst] = stageP[i];
        recRow[dst]   = stageR[i];
    }
}

// -------- per-bucket row sort WITH built-in per-row histogram + scan + ptr emit.
__global__ __launch_bounds__(256) void row_sort(
    const unsigned* __restrict__ recPacked, const unsigned char* __restrict__ recRow,
    const int* __restrict__ bktBase,
    int* __restrict__ ptr, unsigned* __restrict__ edges, int n_rows, int NB)
{
    __shared__ int h0[256], h1[256], sc[256], cur[256];
    const int b = blockIdx.x;
    const int half = blockIdx.y;
    const int tid = threadIdx.x;
    const int r0 = b << 8;
    const int start = bktBase[b], end = bktBase[b + 1];
    const int mid = start + ((end - start) >> 1);

    h0[tid] = 0; h1[tid] = 0;
    __syncthreads();

    for (int i = start + tid; i < end; i += 256) {
        int r = (int)recRow[i];
        if (i < mid) atomicAdd(&h0[r], 1);
        else         atomicAdd(&h1[r], 1);
    }
    __syncthreads();

    const int tot = h0[tid] + h1[tid];
    sc[tid] = tot;
    __syncthreads();
    for (int o = 1; o < 256; o <<= 1) {
        int add = (tid >= o) ? sc[tid - o] : 0;
        __syncthreads();
        sc[tid] += add;
        __syncthreads();
    }
    const int excl = sc[tid] - tot;

    if (half == 0) {
        int grow = r0 + tid;
        if (grow < n_rows) ptr[grow] = start + excl;
        if (b == NB - 1 && tid == 0) ptr[n_rows] = end;
    }
    cur[tid] = excl + (half ? h0[tid] : 0);
    __syncthreads();

    const int s0 = half ? mid : start;
    const int s1 = half ? end : mid;
    for (int i = s0 + tid; i < s1; i += 256) {
        unsigned pk = recPacked[i];
        int r = (int)recRow[i];
        int dst = start + atomicAdd(&cur[r], 1);
        edges[dst] = pk;
    }
}

// -------- Pull SpMM v2: one wave per output row; 8 edges per iteration.
__global__ __launch_bounds__(256) void pull_spmm(
    const unsigned short* __restrict__ tab0,
    const int* __restrict__ ptr, const unsigned* __restrict__ edges,
    unsigned short* __restrict__ tabF, int S_, int n_rows)
{
    const int w = blockIdx.x * 4 + (threadIdx.x >> 6);
    if (w >= n_rows) return;
    const int lane = threadIdx.x & 63;
    const int g = lane >> 3;      // 8 edge-groups
    const int s = lane & 7;       // k-range 8s..8s+7

    const unsigned short* Xs = tab0 + ((w < S_) ? ((size_t)S_ << 6) : (size_t)0)
                                    + (size_t)s * 8;

    float acc[8];
    #pragma unroll
    for (int i = 0; i < 8; ++i) acc[i] = 0.f;

    int e = ptr[w];
    const int ee = ptr[w + 1];
    unsigned u = (e + lane < ee) ? edges[e + lane] : 0u;
    while (e < ee) {
        int m = ee - e; if (m > 64) m = 64;
        unsigned un = (e + 64 + lane < ee) ? edges[e + 64 + lane] : 0u;  // prefetch
        int iters = (m + 7) >> 3;
        #pragma unroll 4
        for (int jj = 0; jj < iters; ++jj) {
            unsigned uj = __shfl(u, jj * 8 + g);     // 0-word: col 0, val 0 -> harmless
            float v = __uint_as_float(uj << 16);     // low 16 = bf16 val
            uint4 xv = *(const uint4*)(Xs + (((size_t)(uj >> 16)) << 6));
            acc[0] = fmaf(v, bf16lo(xv.x), acc[0]);
            acc[1] = fmaf(v, bf16hi(xv.x), acc[1]);
            acc[2] = fmaf(v, bf16lo(xv.y), acc[2]);
            acc[3] = fmaf(v, bf16hi(xv.y), acc[3]);
            acc[4] = fmaf(v, bf16lo(xv.z), acc[4]);
            acc[5] = fmaf(v, bf16hi(xv.z), acc[5]);
            acc[6] = fmaf(v, bf16lo(xv.w), acc[6]);
            acc[7] = fmaf(v, bf16hi(xv.w), acc[7]);
        }
        u = un;
        e += m;
    }

    #pragma unroll
    for (int i = 0; i < 8; ++i) {
        acc[i] += __shfl_xor(acc[i], 8);
        acc[i] += __shfl_xor(acc[i], 16);
        acc[i] += __shfl_xor(acc[i], 32);
    }

    if (g == 0) {
        const uint4 x0 = *(const uint4*)(tab0 + ((size_t)w << 6) + (size_t)s * 8);
        uint4 o;
        o.x = pack2bf16(acc[0] + bf16lo(x0.x), acc[1] + bf16hi(x0.x));
        o.y = pack2bf16(acc[2] + bf16lo(x0.y), acc[3] + bf16hi(x0.y));
        o.z = pack2bf16(acc[4] + bf16lo(x0.z), acc[5] + bf16hi(x0.z));
        o.w = pack2bf16(acc[6] + bf16lo(x0.w), acc[7] + bf16hi(x0.w));
        *(uint4*)(tabF + ((size_t)w << 6) + (size_t)s * 8) = o;
    }
}

// -------- MFMA tail: gather -> GEMM1(64x256x64) -> GEMM2(64x128x256) -> dot.
__global__ __launch_bounds__(256, 1) void tail_mlp(
    const unsigned short* __restrict__ tabF,
    const float* __restrict__ discW,
    const unsigned short* __restrict__ W1t, const float* __restrict__ b1,
    const unsigned short* __restrict__ W2t, const float* __restrict__ b2,
    const float* __restrict__ w3r, const float* __restrict__ b3,
    const float* __restrict__ kn, const int* __restrict__ stu_id,
    const int* __restrict__ exer_id, float* __restrict__ out, int S_, int B)
{
    __shared__ __align__(16) unsigned short xs_bf[64][72];   // 9.0 KB (pad: 2-way banks)
    __shared__ __align__(16) unsigned short h1s[64][264];    // 33.0 KB
    __shared__ __align__(16) unsigned short h2s[64][136];    // 17.0 KB
    __shared__ float b1s[256], b2s[128], w3s[128];
    const int tid = threadIdx.x;
    const int b0 = blockIdx.x * 64;

    b1s[tid] = b1[tid];
    if (tid < 128) { b2s[tid] = b2[tid]; w3s[tid] = w3r[tid]; }

    // ---- phase 0: x = disc*(stat-diff)/3*kn -> bf16 LDS tile (vectorized x4)
    #pragma unroll
    for (int i = 0; i < 4; ++i) {
        int e4 = (i * 256 + tid) * 4;
        int r = e4 >> 6, k0 = e4 & 63;
        int b = b0 + r;
        float4 x4 = make_float4(0.f, 0.f, 0.f, 0.f);
        if (b < B) {
            int sid = stu_id[b], eid = exer_id[b];
            float c = sigmoidf_(discW[eid]) * (1.f / 3.f);
            ushort4 st4 = *((const ushort4*)(tabF + (size_t)sid * 64 + k0));
            ushort4 df4 = *((const ushort4*)(tabF + ((size_t)(S_ + eid)) * 64 + k0));
            float4 kn4 = *((const float4*)(kn + (size_t)b * 64 + k0));
            x4.x = c * (bf16u_to_f(st4.x) - bf16u_to_f(df4.x)) * kn4.x;
            x4.y = c * (bf16u_to_f(st4.y) - bf16u_to_f(df4.y)) * kn4.y;
            x4.z = c * (bf16u_to_f(st4.z) - bf16u_to_f(df4.z)) * kn4.z;
            x4.w = c * (bf16u_to_f(st4.w) - bf16u_to_f(df4.w)) * kn4.w;
        }
        ushort4 xb;
        xb.x = f_to_bf16u(x4.x); xb.y = f_to_bf16u(x4.y);
        xb.z = f_to_bf16u(x4.z); xb.w = f_to_bf16u(x4.w);
        *((ushort4*)&xs_bf[r][k0]) = xb;
    }
    __syncthreads();

    const int w  = tid >> 6;
    const int l  = tid & 63;
    const int lr = l & 15;        // A row / B col / C col
    const int lg = l >> 4;        // k-group (8 contig k each)

    // ---- GEMM1: H1 = sigmoid(X[64x64] @ W1r[64x256] + b1)
    {
        short8v a0 = *(const short8v*)&xs_bf[16 * w + lr][lg * 8];
        short8v a1 = *(const short8v*)&xs_bf[16 * w + lr][32 + lg * 8];
        const unsigned short* w1base = W1t + (size_t)lr * 64 + lg * 8;
        #pragma unroll 4
        for (int n = 0; n < 16; ++n) {
            short8v bb0 = *(const short8v*)(w1base + n * 1024);
            short8v bb1 = *(const short8v*)(w1base + n * 1024 + 32);
            f32x4 acc = {0.f, 0.f, 0.f, 0.f};
            acc = __builtin_amdgcn_mfma_f32_16x16x32_bf16(a0, bb0, acc, 0, 0, 0);
            acc = __builtin_amdgcn_mfma_f32_16x16x32_bf16(a1, bb1, acc, 0, 0, 0);
            int col = n * 16 + lr;
            float bias = b1s[col];
            #pragma unroll
            for (int q = 0; q < 4; ++q)
                h1s[16 * w + lg * 4 + q][col] = f_to_bf16u(sigmoidf_(acc[q] + bias));
        }
    }
    __syncthreads();

    // ---- GEMM2: H2 = sigmoid(H1[64x256] @ W2r[256x128] + b2)
    {
        short8v ak[8];
        #pragma unroll
        for (int kk = 0; kk < 8; ++kk)
            ak[kk] = *(const short8v*)&h1s[16 * w + lr][kk * 32 + lg * 8];
        const unsigned short* w2base = W2t + (size_t)lr * 256 + lg * 8;
        #pragma unroll 2
        for (int n = 0; n < 8; ++n) {
            const unsigned short* bp = w2base + (size_t)n * 16 * 256;
            f32x4 acc = {0.f, 0.f, 0.f, 0.f};
            #pragma unroll
            for (int kk = 0; kk < 8; ++kk) {
                short8v bb = *(const short8v*)(bp + kk * 32);
                acc = __builtin_amdgcn_mfma_f32_16x16x32_bf16(ak[kk], bb, acc, 0, 0, 0);
            }
            int col = n * 16 + lr;
            float bias = b2s[col];
            #pragma unroll
            for (int q = 0; q < 4; ++q)
                h2s[16 * w + lg * 4 + q][col] = f_to_bf16u(sigmoidf_(acc[q] + bias));
        }
    }
    __syncthreads();

    // ---- GEMM3: out = sigmoid(H2 @ w3r + b3)   (64 rows, VALU)
    if (tid < 64) {
        int b = b0 + tid;
        if (b < B) {
            float acc = b3[0];
            const unsigned* h2r = (const unsigned*)&h2s[tid][0];
            #pragma unroll 8
            for (int jj = 0; jj < 64; ++jj) {
                unsigned hv = h2r[jj];
                acc += bf16lo(hv) * w3s[jj * 2 + 0] + bf16hi(hv) * w3s[jj * 2 + 1];
            }
            out[b] = sigmoidf_(acc);
        }
    }
}

extern "C" void kernel_launch(void* const* d_in, const int* in_sizes, int n_in,
                              void* d_out, int out_size, void* d_ws, size_t ws_size,
                              hipStream_t stream) {
    const float* stuW  = (const float*)d_in[0];
    const float* exerW = (const float*)d_in[1];
    const float* knowW = (const float*)d_in[2];
    const float* discW = (const float*)d_in[3];
    const float* W1 = (const float*)d_in[4];
    const float* b1 = (const float*)d_in[5];
    const float* W2 = (const float*)d_in[6];
    const float* b2 = (const float*)d_in[7];
    const float* W3 = (const float*)d_in[8];
    const float* b3 = (const float*)d_in[9];
    const int*   ui1_idx = (const int*)d_in[10];
    const float* ui1_val = (const float*)d_in[11];
    const int*   ui0_idx = (const int*)d_in[12];
    const float* ui0_val = (const float*)d_in[13];
    const int*   iu1_idx = (const int*)d_in[14];
    const float* iu1_val = (const float*)d_in[15];
    const int*   iu0_idx = (const int*)d_in[16];
    const float* iu0_val = (const float*)d_in[17];
    const float* kn      = (const float*)d_in[18];
    const int*   stu_id  = (const int*)d_in[19];
    const int*   exer_id = (const int*)d_in[20];
    float* out = (float*)d_out;

    const int S = in_sizes[0] / KDIM;
    const int E = in_sizes[1] / KDIM;
    const int B = in_sizes[19];
    const int n1 = in_sizes[11], n0 = in_sizes[13];
    const int m1 = in_sizes[15], m0 = in_sizes[17];
    const int ntot = n1 + n0 + m1 + m0;
    const int n_rows = S + E;
    const int NB = (n_rows + 255) / 256;            // 274
    const int nchunks = (ntot + CHUNK - 1) / CHUNK;

    char* p = (char*)d_ws;
    unsigned short* tab0 = (unsigned short*)p; p += (size_t)n_rows * KDIM * 2;   // 8.96 MB
    unsigned* edges      = (unsigned*)p;       p += (size_t)ntot * 4;            // 16 MB (final)
    unsigned* recPacked  = (unsigned*)p;                                         // 16 MB (temp)
    unsigned short* tabF = (unsigned short*)recPacked;   // aliases recPacked: dead before tabF written
    p += (size_t)ntot * 4;
    unsigned char* recRow = (unsigned char*)p; p += (size_t)ntot;                // 4 MB (temp)
    int* ptr    = (int*)p;                     p += (size_t)(n_rows + 1) * 4;
    int* bktCnt = (int*)p;                     p += (size_t)NBPAD * 4;
    int* bktBase= (int*)p;                     p += (size_t)(NBPAD + 1) * 4;
    int* gcurA  = (int*)p;                     p += (size_t)NBPAD * 4;
    p = (char*)(((uintptr_t)p + 255) & ~(uintptr_t)255);     // 16B+ align for vec loads
    unsigned short* W1t = (unsigned short*)p;  p += 256 * 64 * 2;                // 32 KB
    unsigned short* W2t = (unsigned short*)p;  p += 128 * 256 * 2;               // 64 KB
    float* w3r          = (float*)p;           p += 128 * 4;
    unsigned short* knb = (unsigned short*)p;  p += 64 * 64 * 2;                 // 8 KB

    hipMemsetAsync(bktCnt, 0, (size_t)NB * 4, stream);

    prep_w<<<209, 256, 0, stream>>>(W1, W2, W3, knowW, W1t, W2t, w3r, knb);

    embed_mfma<<<(n_rows + 63) / 64, 256, 0, stream>>>(stuW, exerW, knb, tab0, S, n_rows);

    bucket_count<<<nchunks, 256, 0, stream>>>(ui1_idx, ui0_idx, iu1_idx, iu0_idx,
                                              n1, n0, m1, S, bktCnt, ntot, NB);

    scan_tiny<<<1, 256, 0, stream>>>(bktCnt, bktBase, gcurA, NB);

    bin_scatter<<<nchunks, 256, 0, stream>>>(
        ui1_idx, ui1_val, ui0_idx, ui0_val, iu1_idx, iu1_val, iu0_idx, iu0_val,
        n1, n0, m1, m0, S, gcurA, recPacked, recRow, ntot, NB);

    row_sort<<<dim3(NB, 2), 256, 0, stream>>>(recPacked, recRow, bktBase,
                                              ptr, edges, n_rows, NB);

    pull_spmm<<<(n_rows + 3) / 4, 256, 0, stream>>>(tab0, ptr, edges, tabF, S, n_rows);

    tail_mlp<<<(B + 63) / 64, 256, 0, stream>>>(tabF, discW,
                                                W1t, b1, W2t, b2, w3r, b3,
                                                kn, stu_id, exer_id, out, S, B);
}